// Round 1
// baseline (155.790 us; speedup 1.0000x reference)
//
#include <hip/hip_runtime.h>
#include <hip/hip_fp16.h>

// ---------- small vector helpers ----------
struct V3 { float x, y, z; };

__device__ __forceinline__ V3 v3add(V3 a, V3 b){ return {a.x+b.x, a.y+b.y, a.z+b.z}; }
__device__ __forceinline__ V3 v3sub(V3 a, V3 b){ return {a.x-b.x, a.y-b.y, a.z-b.z}; }
__device__ __forceinline__ V3 v3scale(V3 a, float s){ return {a.x*s, a.y*s, a.z*s}; }
__device__ __forceinline__ V3 v3mul(V3 a, V3 b){ return {a.x*b.x, a.y*b.y, a.z*b.z}; }
__device__ __forceinline__ float dot3(V3 a, V3 b){ return fmaf(a.x,b.x, fmaf(a.y,b.y, a.z*b.z)); }
__device__ __forceinline__ V3 nrm3(V3 a){
    float s = rsqrtf(fmaxf(dot3(a,a), 1e-20f));
    return v3scale(a, s);
}

// ---------- texel-count offsets ----------
#define OFF0 0
#define OFF1 1572864
#define OFF2 1966080
#define OFF3 2064384
#define OFF4 2088960
#define OFF5 2095104
#define DIFF_OFF 2096640
#define SPEC_DIFF_COUNT 2098176

// ---- pair layout (mid tier, 16B fp16 pair blocks) ----
struct __align__(16) PairBlock { __half2 h01, h23, h45, h67; };
#define FG_OFF 2098176
#define TOTAL_BLOCKS 2163712
#define PACK_ONLY_BLOCKS 2098176
#define WS_BYTES_FULL  ((size_t)TOTAL_BLOCKS * 16)
#define WS_BYTES_PACK  ((size_t)PACK_ONLY_BLOCKS * 16)

// ---- q10 layout (top tier): 16B quad per texel, 12 x 10-bit UNORM ----
#define Q10_FG_COUNT 65536
#define Q10_COUNT (SPEC_DIFF_COUNT + Q10_FG_COUNT)      // 2,163,712 quads
// appendix: compact 1-uint-per-texel q10 for diffuse(1536) + mip5(1536) = 12,288 B
#define APP_DIFF 0
#define APP_M5   1536
#define APP_UINTS 3072
#define WS_BYTES_Q10M ((size_t)Q10_COUNT * 16 + (size_t)APP_UINTS * 4)  // 34,631,680

// vectorized-pack thread counts (4 quads / 4 texels per thread)
#define Q4_SPEC (SPEC_DIFF_COUNT/4)     // 524,544
#define Q4_FG   (Q10_FG_COUNT/4)        // 16,384
#define Q4_APP  (APP_UINTS/4)           // 768
#define Q4_TOTAL (Q4_SPEC + Q4_FG + Q4_APP)

// ---------- cube face / uv ----------
__device__ __forceinline__ void cube_face_uv(V3 d, int& face, float& u, float& v){
    float ax = fabsf(d.x), ay = fabsf(d.y), az = fabsf(d.z);
    bool is_x = (ax >= ay) && (ax >= az);
    bool is_y = (!is_x) && (ay >= az);
    face = is_x ? (d.x >= 0.f ? 0 : 1)
                : (is_y ? (d.y >= 0.f ? 2 : 3)
                        : (d.z >= 0.f ? 4 : 5));
    float ma = fmaxf(is_x ? ax : (is_y ? ay : az), 1e-20f);
    float un = (face == 0) ? -d.z : (face == 1) ? d.z : (face == 5) ? -d.x : d.x;
    float vn = (face == 2) ?  d.z : (face == 3) ? -d.z : -d.y;
    float inv = 1.0f / ma;
    u = un * inv;
    v = vn * inv;
}

// ---------- bilinear coords ----------
__device__ __forceinline__ void quad_coord_cube(float u, float v, int R,
                                                int& xq, int& yq, float& fx, float& fy){
    float Rf = (float)R;
    float tu = fmaf(fmaf(u, 0.5f, 0.5f), Rf, -0.5f);
    float tv = fmaf(fmaf(v, 0.5f, 0.5f), Rf, -0.5f);
    float x0f = floorf(tu), y0f = floorf(tv);
    fx = tu - x0f; fy = tv - y0f;
    int x0 = (int)x0f, y0 = (int)y0f;
    fx = (x0 < 0) ? 0.f : fx;
    fy = (y0 < 0) ? 0.f : fy;
    xq = min(max(x0, 0), R-1);
    yq = min(max(y0, 0), R-1);
}

__device__ __forceinline__ void quad_coord_2d(float u, float v, int W, int H,
                                              int& xq, int& yq, float& fx, float& fy){
    float tu = fmaf(u, (float)W, -0.5f);
    float tv = fmaf(v, (float)H, -0.5f);
    float x0f = floorf(tu), y0f = floorf(tv);
    fx = tu - x0f; fy = tv - y0f;
    int x0 = (int)x0f, y0 = (int)y0f;
    fx = (x0 < 0) ? 0.f : fx;
    fy = (y0 < 0) ? 0.f : fy;
    xq = min(max(x0, 0), W-1);
    yq = min(max(y0, 0), H-1);
}

// ---------- q10 blend (4 packed texels: 00,01,10,11) ----------
__device__ __forceinline__ V3 q10_blend(uint4 q, float fx, float fy){
    float w00 = (1.f-fx)*(1.f-fy), w01 = fx*(1.f-fy);
    float w10 = (1.f-fx)*fy,       w11 = fx*fy;
    float r = (float)(q.x & 1023u)*w00 + (float)(q.y & 1023u)*w01
            + (float)(q.z & 1023u)*w10 + (float)(q.w & 1023u)*w11;
    float g = (float)((q.x>>10) & 1023u)*w00 + (float)((q.y>>10) & 1023u)*w01
            + (float)((q.z>>10) & 1023u)*w10 + (float)((q.w>>10) & 1023u)*w11;
    float b = (float)((q.x>>20) & 1023u)*w00 + (float)((q.y>>20) & 1023u)*w01
            + (float)((q.z>>20) & 1023u)*w10 + (float)((q.w>>20) & 1023u)*w11;
    const float s = 1.0f/1023.0f;
    return { r*s, g*s, b*s };
}

__device__ __forceinline__ void q10_fg(uint4 q, float fx, float fy,
                                       float& fa, float& fb){
    float w00 = (1.f-fx)*(1.f-fy), w01 = fx*(1.f-fy);
    float w10 = (1.f-fx)*fy,       w11 = fx*fy;
    float a00 = (float)(q.x & 1023u),        b00 = (float)((q.x>>10) & 1023u);
    float a01 = (float)((q.x>>20) & 1023u),  b01 = (float)(q.y & 1023u);
    float a10 = (float)((q.y>>10) & 1023u),  b10 = (float)((q.y>>20) & 1023u);
    float a11 = (float)(q.z & 1023u),        b11 = (float)((q.z>>10) & 1023u);
    const float s = 1.0f/1023.0f;
    fa = (a00*w00 + a01*w01 + a10*w10 + a11*w11) * s;
    fb = (b00*w00 + b01*w01 + b10*w10 + b11*w11) * s;
}

// ---------- LDS compact-q10 bilinear (4-corner clamp) ----------
__device__ __forceinline__ V3 lds_bilin(const unsigned* lds, int base, int R,
                                        int face, float u, float v){
    float Rf = (float)R;
    float tu = fmaf(fmaf(u, 0.5f, 0.5f), Rf, -0.5f);
    float tv = fmaf(fmaf(v, 0.5f, 0.5f), Rf, -0.5f);
    float x0f = floorf(tu), y0f = floorf(tv);
    float fx = tu - x0f, fy = tv - y0f;
    int x0 = min(max((int)x0f,     0), R-1);
    int x1 = min(max((int)x0f + 1, 0), R-1);
    int y0 = min(max((int)y0f,     0), R-1);
    int y1 = min(max((int)y0f + 1, 0), R-1);
    const unsigned* fb = lds + base + face * R * R;
    uint4 q = make_uint4(fb[y0*R + x0], fb[y0*R + x1],
                         fb[y1*R + x0], fb[y1*R + x1]);
    // when (int)x0f<0 both x-corners clamp to 0 so fx value is irrelevant; same for y
    return q10_blend(q, fx, fy);
}

// ---------- pair-layout sampling (mid tier) ----------
__device__ __forceinline__ void pair_extract(const PairBlock& pb, V3& lo, V3& hi){
    lo.x = __low2float(pb.h01);  lo.y = __high2float(pb.h01); lo.z = __low2float(pb.h23);
    hi.x = __high2float(pb.h23); hi.y = __low2float(pb.h45);  hi.z = __high2float(pb.h45);
}

__device__ __forceinline__ V3 bilinear_pairtex(const PairBlock* __restrict__ lvl, int R,
                                               int face, float u, float v){
    float Rf = (float)R;
    float tu = fmaf(fmaf(u, 0.5f, 0.5f), Rf, -0.5f);
    float tv = fmaf(fmaf(v, 0.5f, 0.5f), Rf, -0.5f);
    float x0f = floorf(tu), y0f = floorf(tv);
    float fx = tu - x0f,    fy = tv - y0f;
    int x0 = (int)x0f;
    fx = (x0 < 0) ? 0.f : fx;
    int xb  = min(max(x0, 0), R-1);
    int y0i = min(max((int)y0f,     0), R-1);
    int y1i = min(max((int)y0f + 1, 0), R-1);
    const PairBlock* fb = lvl + (size_t)face * R * R;
    PairBlock b0 = fb[(size_t)y0i * R + xb];
    PairBlock b1 = fb[(size_t)y1i * R + xb];
    V3 l0, h0, l1, h1;
    pair_extract(b0, l0, h0);
    pair_extract(b1, l1, h1);
    V3 r0 = { l0.x + (h0.x-l0.x)*fx, l0.y + (h0.y-l0.y)*fx, l0.z + (h0.z-l0.z)*fx };
    V3 r1 = { l1.x + (h1.x-l1.x)*fx, l1.y + (h1.y-l1.y)*fx, l1.z + (h1.z-l1.z)*fx };
    return { r0.x + (r1.x-r0.x)*fy, r0.y + (r1.y-r0.y)*fy, r0.z + (r1.z-r0.z)*fy };
}

__device__ __forceinline__ void sample_fg_pair(const float4* __restrict__ fgp,
                                               float u, float v, float& fa, float& fb){
    const int W = 256, H = 256;
    float tu = fmaf(u, (float)W, -0.5f);
    float tv = fmaf(v, (float)H, -0.5f);
    float x0f = floorf(tu), y0f = floorf(tv);
    float fx = tu - x0f,    fy = tv - y0f;
    int x0 = (int)x0f;
    fx = (x0 < 0) ? 0.f : fx;
    int xb  = min(max(x0, 0), W-1);
    int y0i = min(max((int)y0f,     0), H-1);
    int y1i = min(max((int)y0f + 1, 0), H-1);
    float4 r0 = fgp[(size_t)y0i * W + xb];
    float4 r1 = fgp[(size_t)y1i * W + xb];
    float t0a = r0.x + (r0.z - r0.x)*fx, t0b = r0.y + (r0.w - r0.y)*fx;
    float t1a = r1.x + (r1.z - r1.x)*fx, t1b = r1.y + (r1.w - r1.y)*fx;
    fa = t0a + (t1a - t0a)*fy;
    fb = t0b + (t1b - t0b)*fy;
}

// ---------- raw-tier sampling ----------
__device__ __forceinline__ V3 bilinear_cube3(const float* __restrict__ tex, int R,
                                             int face, float u, float v){
    float Rf = (float)R;
    float tu = fmaf(fmaf(u, 0.5f, 0.5f), Rf, -0.5f);
    float tv = fmaf(fmaf(v, 0.5f, 0.5f), Rf, -0.5f);
    float x0 = floorf(tu), y0 = floorf(tv);
    float fx = tu - x0,    fy = tv - y0;
    int x0i = min(max((int)x0,     0), R-1);
    int x1i = min(max((int)x0 + 1, 0), R-1);
    int y0i = min(max((int)y0,     0), R-1);
    int y1i = min(max((int)y0 + 1, 0), R-1);
    const float* base = tex + (size_t)face * R * R * 3;
    const float* r0 = base + (size_t)y0i * R * 3;
    const float* r1 = base + (size_t)y1i * R * 3;
    float a0 = r0[3*x0i], a1 = r0[3*x0i+1], a2 = r0[3*x0i+2];
    float b0 = r0[3*x1i], b1 = r0[3*x1i+1], b2 = r0[3*x1i+2];
    float d0 = r1[3*x0i], d1 = r1[3*x0i+1], d2 = r1[3*x0i+2];
    float e0 = r1[3*x1i], e1 = r1[3*x1i+1], e2 = r1[3*x1i+2];
    float w00 = (1.f-fx)*(1.f-fy), w01 = fx*(1.f-fy);
    float w10 = (1.f-fx)*fy,       w11 = fx*fy;
    V3 out;
    out.x = a0*w00 + b0*w01 + d0*w10 + e0*w11;
    out.y = a1*w00 + b1*w01 + d1*w10 + e1*w11;
    out.z = a2*w00 + b2*w01 + d2*w10 + e2*w11;
    return out;
}

__device__ __forceinline__ void sample_fg(const float* __restrict__ lut,
                                          float u, float v, float& fa, float& fb){
    const int W = 256, H = 256;
    float tu = fmaf(u, (float)W, -0.5f);
    float tv = fmaf(v, (float)H, -0.5f);
    float x0 = floorf(tu), y0 = floorf(tv);
    float fx = tu - x0,    fy = tv - y0;
    int x0i = min(max((int)x0,     0), W-1);
    int x1i = min(max((int)x0 + 1, 0), W-1);
    int y0i = min(max((int)y0,     0), H-1);
    int y1i = min(max((int)y0 + 1, 0), H-1);
    const float2* l2 = (const float2*)lut;
    float2 a = l2[(size_t)y0i*W + x0i];
    float2 b = l2[(size_t)y0i*W + x1i];
    float2 d = l2[(size_t)y1i*W + x0i];
    float2 e = l2[(size_t)y1i*W + x1i];
    float w00 = (1.f-fx)*(1.f-fy), w01 = fx*(1.f-fy);
    float w10 = (1.f-fx)*fy,       w11 = fx*fy;
    fa = a.x*w00 + b.x*w01 + d.x*w10 + e.x*w11;
    fb = a.y*w00 + b.y*w01 + d.y*w10 + e.y*w11;
}

// ---------- linear -> srgb ----------
__device__ __forceinline__ float lin2srgb(float x){
    float xs = (x > 0.0031308f) ? x : 1.0f;
    float p  = __builtin_amdgcn_exp2f(__builtin_amdgcn_logf(xs) * (1.0f/2.4f));
    return (x > 0.0031308f) ? fmaf(1.055f, p, -0.055f) : 12.92f * x;
}

__device__ __forceinline__ float clamp01(float x){ return fminf(fmaxf(x, 0.f), 1.f); }

// ---------- per-pixel precomputed state ----------
struct PixPre {
    V3 diff_alb, spec_alb;
    int sface; float su, sv;
    int dface; float du, dv;
    int offA, RA, offB, RB; float f;
    float ndotv, rough;
};

__device__ __forceinline__ PixPre pre_pixel_v(V3 pos, V3 nrm, V3 bc, float m, float r, V3 vp)
{
    V3 wo = nrm3(v3sub(vp, pos));
    float ndv_raw = dot3(wo, nrm);
    V3 refl = nrm3(v3sub(v3scale(nrm, 2.0f*ndv_raw), wo));

    PixPre p;
    float one_m = 1.0f - m;
    p.diff_alb = v3scale(bc, one_m);
    p.spec_alb = { fmaf(m, bc.x, 0.04f*one_m),
                   fmaf(m, bc.y, 0.04f*one_m),
                   fmaf(m, bc.z, 0.04f*one_m) };
    p.ndotv = fmaxf(ndv_raw, 0.0001f);
    p.rough = r;

    const float MIN_R = 0.08f, MAX_R = 0.5f;
    float lo = (fminf(fmaxf(r, MIN_R), MAX_R) - MIN_R) / (MAX_R - MIN_R) * 4.0f;
    float hi = (fminf(fmaxf(r, MAX_R), 1.0f) - MAX_R) / (1.0f - MAX_R) + 4.0f;
    float mip = (r < MAX_R) ? lo : hi;
    mip = fminf(fmaxf(mip, 0.0f), 5.0f);
    int l0 = min((int)mip, 5);
    p.f = mip - (float)l0;
    int l1 = min(l0 + 1, 5);

    int offA = OFF0;
    offA = (l0 == 1) ? OFF1 : offA; offA = (l0 == 2) ? OFF2 : offA;
    offA = (l0 == 3) ? OFF3 : offA; offA = (l0 == 4) ? OFF4 : offA;
    offA = (l0 == 5) ? OFF5 : offA;
    int offB = OFF0;
    offB = (l1 == 1) ? OFF1 : offB; offB = (l1 == 2) ? OFF2 : offB;
    offB = (l1 == 3) ? OFF3 : offB; offB = (l1 == 4) ? OFF4 : offB;
    offB = (l1 == 5) ? OFF5 : offB;
    p.offA = offA; p.RA = 512 >> l0;
    p.offB = offB; p.RB = 512 >> l1;

    cube_face_uv(nrm, p.dface, p.du, p.dv);
    cube_face_uv(refl, p.sface, p.su, p.sv);
    return p;
}

__device__ __forceinline__ PixPre pre_pixel(
    int i,
    const float* __restrict__ gb_pos, const float* __restrict__ gb_normal,
    const float* __restrict__ basecolor, const float* __restrict__ metallic,
    const float* __restrict__ roughness, V3 vp)
{
    V3 pos = { gb_pos[3*i],    gb_pos[3*i+1],    gb_pos[3*i+2] };
    V3 nrm = { gb_normal[3*i], gb_normal[3*i+1], gb_normal[3*i+2] };
    V3 bc  = { basecolor[3*i], basecolor[3*i+1], basecolor[3*i+2] };
    return pre_pixel_v(pos, nrm, bc, metallic[i], roughness[i], vp);
}

// ---------- q10 pack helper ----------
__device__ __forceinline__ unsigned pk3(float a, float b, float c){
    unsigned ia = __float2uint_rn(fminf(fmaxf(a, 0.f), 1.f) * 1023.f);
    unsigned ib = __float2uint_rn(fminf(fmaxf(b, 0.f), 1.f) * 1023.f);
    unsigned ic = __float2uint_rn(fminf(fmaxf(c, 0.f), 1.f) * 1023.f);
    return ia | (ib << 10) | (ic << 20);
}

// ---------- vectorized q10+appendix pre-pass: 4 quads (or 4 texels) per thread ----------
// All region boundaries (OFF1..OFF5, DIFF_OFF, SPEC_DIFF_COUNT, APP_M5) are multiples
// of 4, and every level has R % 4 == 0, so a 4-quad group never crosses a region or a
// row boundary. 3*local floats with local % 4 == 0 -> 48B-aligned float4 loads.
__global__ __launch_bounds__(256)
void pack_q10m_v4(const float* __restrict__ s0, const float* __restrict__ s1,
                  const float* __restrict__ s2, const float* __restrict__ s3,
                  const float* __restrict__ s4, const float* __restrict__ s5,
                  const float* __restrict__ diffuse, const float* __restrict__ fg_lut,
                  uint4* __restrict__ qws)
{
    int t = blockIdx.x * blockDim.x + threadIdx.x;
    if (t >= Q4_TOTAL) return;

    if (t >= Q4_SPEC + Q4_FG) {
        // appendix: 4 compact texels (diffuse then mip5); boundary APP_M5=1536 is /4
        int local4 = (t - Q4_SPEC - Q4_FG) * 4;
        const float* src; int idx;
        if (local4 < APP_M5) { src = diffuse; idx = local4; }
        else                 { src = s5;      idx = local4 - APP_M5; }
        const float4* sp = (const float4*)(src + 3*idx);
        float4 a = sp[0], b = sp[1], c = sp[2];
        uint4 o;
        o.x = pk3(a.x, a.y, a.z);
        o.y = pk3(a.w, b.x, b.y);
        o.z = pk3(b.z, b.w, c.x);
        o.w = pk3(c.y, c.z, c.w);
        *(uint4*)((unsigned*)(qws + Q10_COUNT) + local4) = o;
        return;
    }

    if (t >= Q4_SPEC) {
        // fg region: 4 quads along a row. texels x..x+4 of rows y and min(y+1,255).
        int local = (t - Q4_SPEC) * 4;
        int x = local & 255, y = local >> 8;
        int y1 = (y == 255) ? y : y + 1;
        const float* r0p = fg_lut + 2*local;
        const float* r1p = fg_lut + 2*((y1 << 8) + x);
        bool edge = (x == 252);                  // x+4 would clamp (x%4==0, so only 252)
        float4 r0a = ((const float4*)r0p)[0], r0b = ((const float4*)r0p)[1];
        float4 r1a = ((const float4*)r1p)[0], r1b = ((const float4*)r1p)[1];
        float4 r0c = *(const float4*)(r0p + (edge ? 4 : 8));   // texel x+4 (a,b) in .x,.y
        float4 r1c = *(const float4*)(r1p + (edge ? 4 : 8));
        float a0[5], b0[5], a1[5], b1[5];
        a0[0]=r0a.x; b0[0]=r0a.y; a0[1]=r0a.z; b0[1]=r0a.w;
        a0[2]=r0b.x; b0[2]=r0b.y; a0[3]=r0b.z; b0[3]=r0b.w;
        a0[4]= edge ? r0b.z : r0c.x; b0[4]= edge ? r0b.w : r0c.y;
        a1[0]=r1a.x; b1[0]=r1a.y; a1[1]=r1a.z; b1[1]=r1a.w;
        a1[2]=r1b.x; b1[2]=r1b.y; a1[3]=r1b.z; b1[3]=r1b.w;
        a1[4]= edge ? r1b.z : r1c.x; b1[4]= edge ? r1b.w : r1c.y;
        #pragma unroll
        for (int k = 0; k < 4; ++k) {
            uint4 q;
            q.x = pk3(a0[k], b0[k], a0[k+1]);
            q.y = pk3(b0[k+1], a1[k], b1[k]);
            q.z = pk3(a1[k+1], b1[k+1], 0.f);
            q.w = 0u;
            qws[(size_t)SPEC_DIFF_COUNT + local + k] = q;
        }
        return;
    }

    // spec/diffuse quad region: 4 quads along a row
    int local4q = t * 4;
    const float* src; int local; int Rm;
    if      (local4q >= DIFF_OFF) { src = diffuse; local = local4q - DIFF_OFF; Rm = 15;  }
    else if (local4q >= OFF5)     { src = s5;      local = local4q - OFF5;     Rm = 15;  }
    else if (local4q >= OFF4)     { src = s4;      local = local4q - OFF4;     Rm = 31;  }
    else if (local4q >= OFF3)     { src = s3;      local = local4q - OFF3;     Rm = 63;  }
    else if (local4q >= OFF2)     { src = s2;      local = local4q - OFF2;     Rm = 127; }
    else if (local4q >= OFF1)     { src = s1;      local = local4q - OFF1;     Rm = 255; }
    else                          { src = s0;      local = local4q;            Rm = 511; }
    int x = local & Rm;
    int y = (local / (Rm + 1)) & Rm;
    int rowUp = (y == Rm) ? 0 : (Rm + 1);
    const float* r0p = src + 3*local;
    const float* r1p = src + 3*(local + rowUp);
    bool edge = (x + 4 > Rm);                    // x%4==0 -> only x == R-4
    // texels x..x+3 : 12 floats, 48B-aligned
    float4 A0 = ((const float4*)r0p)[0], A1 = ((const float4*)r0p)[1], A2 = ((const float4*)r0p)[2];
    float4 B0 = ((const float4*)r1p)[0], B1 = ((const float4*)r1p)[1], B2 = ((const float4*)r1p)[2];
    // texel x+4 rgb (only consumed when !edge; edge-safe address when edge)
    float4 A3 = *(const float4*)(r0p + (edge ? 8 : 12));
    float4 B3 = *(const float4*)(r1p + (edge ? 8 : 12));
    unsigned t0[5], t1[5];
    t0[0] = pk3(A0.x, A0.y, A0.z);
    t0[1] = pk3(A0.w, A1.x, A1.y);
    t0[2] = pk3(A1.z, A1.w, A2.x);
    t0[3] = pk3(A2.y, A2.z, A2.w);
    t0[4] = edge ? t0[3] : pk3(A3.x, A3.y, A3.z);
    t1[0] = pk3(B0.x, B0.y, B0.z);
    t1[1] = pk3(B0.w, B1.x, B1.y);
    t1[2] = pk3(B1.z, B1.w, B2.x);
    t1[3] = pk3(B2.y, B2.z, B2.w);
    t1[4] = edge ? t1[3] : pk3(B3.x, B3.y, B3.z);
    #pragma unroll
    for (int k = 0; k < 4; ++k) {
        uint4 q;
        q.x = t0[k];
        q.y = t0[k+1];
        q.z = t1[k];
        q.w = t1[k+1];
        qws[(size_t)local4q + k] = q;
    }
}

// ---------- spec sampler: LDS for mip5 (R==16), global quads otherwise ----------
__device__ __forceinline__ V3 sample_spec(const uint4* __restrict__ qws,
                                          const unsigned* lds,
                                          int off, int R, int face, float u, float v){
    if (R == 16)
        return lds_bilin(lds, APP_M5, 16, face, u, v);
    int x, y; float fx, fy;
    quad_coord_cube(u, v, R, x, y, fx, fy);
    size_t q = (size_t)off + (size_t)face * R * R + (size_t)y * R + x;
    return q10_blend(qws[q], fx, fy);
}

// ---------- full per-pixel shade ----------
__device__ __forceinline__ void shade_px(V3 pos, V3 nrm, V3 bc, float m, float r, V3 vp,
                                         const uint4* __restrict__ qws,
                                         const unsigned* lds, float* o)
{
    PixPre p = pre_pixel_v(pos, nrm, bc, m, r, vp);

    // fg (global, L2-resident) — issue first
    int fx_, fy_; float ffx, ffy;
    quad_coord_2d(p.ndotv, p.rough, 256, 256, fx_, fy_, ffx, ffy);
    uint4 F = qws[(size_t)SPEC_DIFF_COUNT + (size_t)fy_ * 256 + fx_];

    V3 specA = sample_spec(qws, lds, p.offA, p.RA, p.sface, p.su, p.sv);
    V3 specB = sample_spec(qws, lds, p.offB, p.RB, p.sface, p.su, p.sv);
    V3 ambient = lds_bilin(lds, APP_DIFF, 16, p.dface, p.du, p.dv);

    float fa, fb;
    q10_fg(F, ffx, ffy, fa, fb);

    V3 spec = { specA.x + (specB.x - specA.x) * p.f,
                specA.y + (specB.y - specA.y) * p.f,
                specA.z + (specB.z - specA.z) * p.f };
    V3 reflc = { fmaf(p.spec_alb.x, fa, fb),
                 fmaf(p.spec_alb.y, fa, fb),
                 fmaf(p.spec_alb.z, fa, fb) };
    V3 rgb = v3add(v3mul(spec, reflc), v3mul(ambient, p.diff_alb));

    o[0] = lin2srgb(clamp01(rgb.x));
    o[1] = lin2srgb(clamp01(rgb.y));
    o[2] = lin2srgb(clamp01(rgb.z));
}

// ---------- q10+small-LDS main kernel: 4 px/thread, vectorized gbuffer I/O ----------
__global__ __launch_bounds__(256)
void envlight_q10m_v4(const float* __restrict__ gb_pos,
                      const float* __restrict__ gb_normal,
                      const float* __restrict__ basecolor,
                      const float* __restrict__ metallic,
                      const float* __restrict__ roughness,
                      const float* __restrict__ view_pos,
                      const uint4* __restrict__ qws,
                      float* __restrict__ out,
                      int n)
{
    __shared__ unsigned lds_small[APP_UINTS];   // 12 KB: diffuse + mip5
    {
        const uint4* app4 = qws + Q10_COUNT;
        uint4* l4 = (uint4*)lds_small;
        for (int k = threadIdx.x; k < APP_UINTS/4; k += 256)
            l4[k] = app4[k];
    }
    __syncthreads();

    int t = blockIdx.x * blockDim.x + threadIdx.x;
    int i0 = t * 4;
    if (i0 >= n) return;
    V3 vp = { view_pos[0], view_pos[1], view_pos[2] };

    if (i0 + 3 < n) {
        // i0 % 4 == 0  ->  3*i0 floats is 48B-aligned: 3 aligned float4 per array
        const float4* P = (const float4*)(gb_pos    + 3*i0);
        const float4* N = (const float4*)(gb_normal + 3*i0);
        const float4* B = (const float4*)(basecolor + 3*i0);
        float4 p0 = P[0], p1 = P[1], p2 = P[2];
        float4 n0 = N[0], n1 = N[1], n2 = N[2];
        float4 b0 = B[0], b1 = B[1], b2 = B[2];
        float4 mt = *(const float4*)(metallic  + i0);
        float4 rg = *(const float4*)(roughness + i0);

        float pf[12] = { p0.x,p0.y,p0.z,p0.w, p1.x,p1.y,p1.z,p1.w, p2.x,p2.y,p2.z,p2.w };
        float nf[12] = { n0.x,n0.y,n0.z,n0.w, n1.x,n1.y,n1.z,n1.w, n2.x,n2.y,n2.z,n2.w };
        float bf[12] = { b0.x,b0.y,b0.z,b0.w, b1.x,b1.y,b1.z,b1.w, b2.x,b2.y,b2.z,b2.w };
        float mf[4]  = { mt.x, mt.y, mt.z, mt.w };
        float rf[4]  = { rg.x, rg.y, rg.z, rg.w };
        float of[12];

        #pragma unroll
        for (int j = 0; j < 4; ++j) {
            V3 pos = { pf[3*j], pf[3*j+1], pf[3*j+2] };
            V3 nrm = { nf[3*j], nf[3*j+1], nf[3*j+2] };
            V3 bc  = { bf[3*j], bf[3*j+1], bf[3*j+2] };
            shade_px(pos, nrm, bc, mf[j], rf[j], vp, qws, lds_small, of + 3*j);
        }

        float4* O = (float4*)(out + 3*i0);
        O[0] = make_float4(of[0], of[1], of[2],  of[3]);
        O[1] = make_float4(of[4], of[5], of[6],  of[7]);
        O[2] = make_float4(of[8], of[9], of[10], of[11]);
    } else {
        for (int j = 0; j < 4; ++j) {
            int i = i0 + j;
            if (i >= n) break;
            V3 pos = { gb_pos[3*i],    gb_pos[3*i+1],    gb_pos[3*i+2] };
            V3 nrm = { gb_normal[3*i], gb_normal[3*i+1], gb_normal[3*i+2] };
            V3 bc  = { basecolor[3*i], basecolor[3*i+1], basecolor[3*i+2] };
            float o[3];
            shade_px(pos, nrm, bc, metallic[i], roughness[i], vp, qws, lds_small, o);
            out[3*i+0] = o[0]; out[3*i+1] = o[1]; out[3*i+2] = o[2];
        }
    }
}

// ---------- pair pre-pass (mid tier) ----------
__global__ __launch_bounds__(256)
void pack_kernel(const float* __restrict__ s0, const float* __restrict__ s1,
                 const float* __restrict__ s2, const float* __restrict__ s3,
                 const float* __restrict__ s4, const float* __restrict__ s5,
                 const float* __restrict__ diffuse, const float* __restrict__ fg_lut,
                 PairBlock* __restrict__ ws, int total)
{
    int t = blockIdx.x * blockDim.x + threadIdx.x;
    if (t >= total) return;
    if (t >= FG_OFF) {
        int local = t - FG_OFF;
        int x = local & 255;
        int nb = (x == 255) ? local : local + 1;
        float4 v = make_float4(fg_lut[2*local], fg_lut[2*local+1],
                               fg_lut[2*nb],    fg_lut[2*nb+1]);
        ((float4*)ws)[t] = v;
        return;
    }
    const float* src; int local; int Rmask;
    if      (t >= DIFF_OFF) { src = diffuse; local = t - DIFF_OFF; Rmask = 15;  }
    else if (t >= OFF5)     { src = s5;      local = t - OFF5;     Rmask = 15;  }
    else if (t >= OFF4)     { src = s4;      local = t - OFF4;     Rmask = 31;  }
    else if (t >= OFF3)     { src = s3;      local = t - OFF3;     Rmask = 63;  }
    else if (t >= OFF2)     { src = s2;      local = t - OFF2;     Rmask = 127; }
    else if (t >= OFF1)     { src = s1;      local = t - OFF1;     Rmask = 255; }
    else                    { src = s0;      local = t;            Rmask = 511; }
    int nb = ((local & Rmask) == Rmask) ? local : local + 1;
    float ar = src[3*local], ag = src[3*local+1], ab = src[3*local+2];
    float br = src[3*nb],    bg = src[3*nb+1],    bb = src[3*nb+2];
    PairBlock pb;
    pb.h01 = __floats2half2_rn(ar, ag);
    pb.h23 = __floats2half2_rn(ab, br);
    pb.h45 = __floats2half2_rn(bg, bb);
    pb.h67 = __floats2half2_rn(0.f, 0.f);
    ws[t] = pb;
}

// ---------- pair main kernel (mid tier) ----------
template <bool FGPAIR>
__global__ __launch_bounds__(256)
void envlight_pair(const float* __restrict__ gb_pos,
                   const float* __restrict__ gb_normal,
                   const float* __restrict__ basecolor,
                   const float* __restrict__ metallic,
                   const float* __restrict__ roughness,
                   const float* __restrict__ view_pos,
                   const float* __restrict__ fg_lut,
                   const PairBlock* __restrict__ ws,
                   float* __restrict__ out,
                   int n)
{
    int i = blockIdx.x * blockDim.x + threadIdx.x;
    if (i >= n) return;
    V3 vp = { view_pos[0], view_pos[1], view_pos[2] };
    PixPre p = pre_pixel(i, gb_pos, gb_normal, basecolor, metallic, roughness, vp);
    V3 specA   = bilinear_pairtex(ws + p.offA, p.RA, p.sface, p.su, p.sv);
    V3 specB   = bilinear_pairtex(ws + p.offB, p.RB, p.sface, p.su, p.sv);
    V3 ambient = bilinear_pairtex(ws + DIFF_OFF, 16, p.dface, p.du, p.dv);
    float fa, fb;
    if (FGPAIR) sample_fg_pair((const float4*)(ws + FG_OFF), p.ndotv, p.rough, fa, fb);
    else        sample_fg(fg_lut, p.ndotv, p.rough, fa, fb);
    V3 spec = { specA.x + (specB.x - specA.x) * p.f,
                specA.y + (specB.y - specA.y) * p.f,
                specA.z + (specB.z - specA.z) * p.f };
    V3 reflc = { fmaf(p.spec_alb.x, fa, fb),
                 fmaf(p.spec_alb.y, fa, fb),
                 fmaf(p.spec_alb.z, fa, fb) };
    V3 rgb = v3add(v3mul(spec, reflc), v3mul(ambient, p.diff_alb));
    out[3*i+0] = lin2srgb(clamp01(rgb.x));
    out[3*i+1] = lin2srgb(clamp01(rgb.y));
    out[3*i+2] = lin2srgb(clamp01(rgb.z));
}

// ---------- raw fallback ----------
__global__ __launch_bounds__(256)
void envlight_fallback(const float* __restrict__ gb_pos,
                       const float* __restrict__ gb_normal,
                       const float* __restrict__ basecolor,
                       const float* __restrict__ metallic,
                       const float* __restrict__ roughness,
                       const float* __restrict__ view_pos,
                       const float* __restrict__ diffuse,
                       const float* __restrict__ fg_lut,
                       const float* __restrict__ s0, const float* __restrict__ s1,
                       const float* __restrict__ s2, const float* __restrict__ s3,
                       const float* __restrict__ s4, const float* __restrict__ s5,
                       float* __restrict__ out, int n)
{
    int i = blockIdx.x * blockDim.x + threadIdx.x;
    if (i >= n) return;
    V3 vp = { view_pos[0], view_pos[1], view_pos[2] };
    PixPre p = pre_pixel(i, gb_pos, gb_normal, basecolor, metallic, roughness, vp);
    int l0 = 0;
    l0 = (p.offA == OFF1) ? 1 : l0; l0 = (p.offA == OFF2) ? 2 : l0;
    l0 = (p.offA == OFF3) ? 3 : l0; l0 = (p.offA == OFF4) ? 4 : l0;
    l0 = (p.offA == OFF5) ? 5 : l0;
    int l1 = 0;
    l1 = (p.offB == OFF1) ? 1 : l1; l1 = (p.offB == OFF2) ? 2 : l1;
    l1 = (p.offB == OFF3) ? 3 : l1; l1 = (p.offB == OFF4) ? 4 : l1;
    l1 = (p.offB == OFF5) ? 5 : l1;
    const float* tA = s0;
    tA = (l0 == 1) ? s1 : tA; tA = (l0 == 2) ? s2 : tA;
    tA = (l0 == 3) ? s3 : tA; tA = (l0 == 4) ? s4 : tA; tA = (l0 == 5) ? s5 : tA;
    const float* tB = s0;
    tB = (l1 == 1) ? s1 : tB; tB = (l1 == 2) ? s2 : tB;
    tB = (l1 == 3) ? s3 : tB; tB = (l1 == 4) ? s4 : tB; tB = (l1 == 5) ? s5 : tB;
    V3 ambient = bilinear_cube3(diffuse, 16, p.dface, p.du, p.dv);
    V3 specA   = bilinear_cube3(tA, p.RA, p.sface, p.su, p.sv);
    V3 specB   = bilinear_cube3(tB, p.RB, p.sface, p.su, p.sv);
    float fa, fb;
    sample_fg(fg_lut, p.ndotv, p.rough, fa, fb);
    V3 spec = { specA.x + (specB.x - specA.x) * p.f,
                specA.y + (specB.y - specA.y) * p.f,
                specA.z + (specB.z - specA.z) * p.f };
    V3 reflc = { fmaf(p.spec_alb.x, fa, fb),
                 fmaf(p.spec_alb.y, fa, fb),
                 fmaf(p.spec_alb.z, fa, fb) };
    V3 rgb = v3add(v3mul(spec, reflc), v3mul(ambient, p.diff_alb));
    out[3*i+0] = lin2srgb(clamp01(rgb.x));
    out[3*i+1] = lin2srgb(clamp01(rgb.y));
    out[3*i+2] = lin2srgb(clamp01(rgb.z));
}

extern "C" void kernel_launch(void* const* d_in, const int* in_sizes, int n_in,
                              void* d_out, int out_size, void* d_ws, size_t ws_size,
                              hipStream_t stream) {
    const float* gb_pos    = (const float*)d_in[0];
    const float* gb_normal = (const float*)d_in[1];
    const float* basecolor = (const float*)d_in[2];
    const float* metallic  = (const float*)d_in[3];
    const float* roughness = (const float*)d_in[4];
    const float* view_pos  = (const float*)d_in[5];
    const float* diffuse   = (const float*)d_in[6];
    const float* fg_lut    = (const float*)d_in[7];
    const float* s0        = (const float*)d_in[8];
    const float* s1        = (const float*)d_in[9];
    const float* s2        = (const float*)d_in[10];
    const float* s3        = (const float*)d_in[11];
    const float* s4        = (const float*)d_in[12];
    const float* s5        = (const float*)d_in[13];
    float* out = (float*)d_out;

    int n = in_sizes[0] / 3;
    int block = 256;
    int grid = (n + block - 1) / block;

    if (ws_size >= WS_BYTES_Q10M) {
        uint4* qws = (uint4*)d_ws;
        int pgrid = (Q4_TOTAL + block - 1) / block;
        pack_q10m_v4<<<pgrid, block, 0, stream>>>(s0, s1, s2, s3, s4, s5,
                                                  diffuse, fg_lut, qws);
        int t4 = (n + 3) / 4;
        int mgrid = (t4 + block - 1) / block;
        envlight_q10m_v4<<<mgrid, block, 0, stream>>>(gb_pos, gb_normal, basecolor,
            metallic, roughness, view_pos, qws, out, n);
    } else if (ws_size >= WS_BYTES_PACK) {
        bool full = ws_size >= WS_BYTES_FULL;
        PairBlock* ws = (PairBlock*)d_ws;
        int total = full ? TOTAL_BLOCKS : PACK_ONLY_BLOCKS;
        int pgrid = (total + block - 1) / block;
        pack_kernel<<<pgrid, block, 0, stream>>>(s0, s1, s2, s3, s4, s5,
                                                 diffuse, fg_lut, ws, total);
        if (full)
            envlight_pair<true><<<grid, block, 0, stream>>>(gb_pos, gb_normal,
                basecolor, metallic, roughness, view_pos, fg_lut, ws, out, n);
        else
            envlight_pair<false><<<grid, block, 0, stream>>>(gb_pos, gb_normal,
                basecolor, metallic, roughness, view_pos, fg_lut, ws, out, n);
    } else {
        envlight_fallback<<<grid, block, 0, stream>>>(gb_pos, gb_normal, basecolor,
            metallic, roughness, view_pos, diffuse, fg_lut,
            s0, s1, s2, s3, s4, s5, out, n);
    }
}

// Round 2
// 151.746 us; speedup vs baseline: 1.0267x; 1.0267x over previous
//
#include <hip/hip_runtime.h>
#include <hip/hip_fp16.h>

// ---------- small vector helpers ----------
struct V3 { float x, y, z; };

__device__ __forceinline__ V3 v3add(V3 a, V3 b){ return {a.x+b.x, a.y+b.y, a.z+b.z}; }
__device__ __forceinline__ V3 v3sub(V3 a, V3 b){ return {a.x-b.x, a.y-b.y, a.z-b.z}; }
__device__ __forceinline__ V3 v3scale(V3 a, float s){ return {a.x*s, a.y*s, a.z*s}; }
__device__ __forceinline__ V3 v3mul(V3 a, V3 b){ return {a.x*b.x, a.y*b.y, a.z*b.z}; }
__device__ __forceinline__ float dot3(V3 a, V3 b){ return fmaf(a.x,b.x, fmaf(a.y,b.y, a.z*b.z)); }
__device__ __forceinline__ V3 nrm3(V3 a){
    float s = rsqrtf(fmaxf(dot3(a,a), 1e-20f));
    return v3scale(a, s);
}

// ---------- quad layout (s0 dropped: raw-sampled in main; s5/diffuse: LDS appendix only) ----------
// quad region (uint4 per texel, 2x2 bilinear footprint):
//   s1 (R=256): [0, 393216)
//   s2 (R=128): [393216, 491520)
//   s3 (R= 64): [491520, 516096)
//   s4 (R= 32): [516096, 522240)
//   fg  (256²): [522240, 587776)
#define NOFF1 0
#define NOFF2 393216
#define NOFF3 491520
#define NOFF4 516096
#define SPEC4_COUNT 522240
#define NFG_OFF 522240
#define NTOT_QUADS 587776
// appendix: compact 1-uint-per-texel q10 for diffuse(1536) + mip5(1536)
#define APP_DIFF 0
#define APP_M5   1536
#define APP_UINTS 3072
#define WS_BYTES_NEW ((size_t)NTOT_QUADS * 16 + (size_t)APP_UINTS * 4)   // 9,416,704

// pack thread counts (4 quads / 4 texels per thread)
#define NQ4_SPEC (SPEC4_COUNT/4)    // 130,560
#define NQ4_FG   (65536/4)          // 16,384
#define NQ4_APP  (APP_UINTS/4)      // 768
#define NQ4_TOTAL (NQ4_SPEC + NQ4_FG + NQ4_APP)   // 147,712 = 577*256

// ---------- cube face / uv ----------
__device__ __forceinline__ void cube_face_uv(V3 d, int& face, float& u, float& v){
    float ax = fabsf(d.x), ay = fabsf(d.y), az = fabsf(d.z);
    bool is_x = (ax >= ay) && (ax >= az);
    bool is_y = (!is_x) && (ay >= az);
    face = is_x ? (d.x >= 0.f ? 0 : 1)
                : (is_y ? (d.y >= 0.f ? 2 : 3)
                        : (d.z >= 0.f ? 4 : 5));
    float ma = fmaxf(is_x ? ax : (is_y ? ay : az), 1e-20f);
    float un = (face == 0) ? -d.z : (face == 1) ? d.z : (face == 5) ? -d.x : d.x;
    float vn = (face == 2) ?  d.z : (face == 3) ? -d.z : -d.y;
    float inv = 1.0f / ma;
    u = un * inv;
    v = vn * inv;
}

// ---------- bilinear coords ----------
__device__ __forceinline__ void quad_coord_cube(float u, float v, int R,
                                                int& xq, int& yq, float& fx, float& fy){
    float Rf = (float)R;
    float tu = fmaf(fmaf(u, 0.5f, 0.5f), Rf, -0.5f);
    float tv = fmaf(fmaf(v, 0.5f, 0.5f), Rf, -0.5f);
    float x0f = floorf(tu), y0f = floorf(tv);
    fx = tu - x0f; fy = tv - y0f;
    int x0 = (int)x0f, y0 = (int)y0f;
    fx = (x0 < 0) ? 0.f : fx;
    fy = (y0 < 0) ? 0.f : fy;
    xq = min(max(x0, 0), R-1);
    yq = min(max(y0, 0), R-1);
}

__device__ __forceinline__ void quad_coord_2d(float u, float v, int W, int H,
                                              int& xq, int& yq, float& fx, float& fy){
    float tu = fmaf(u, (float)W, -0.5f);
    float tv = fmaf(v, (float)H, -0.5f);
    float x0f = floorf(tu), y0f = floorf(tv);
    fx = tu - x0f; fy = tv - y0f;
    int x0 = (int)x0f, y0 = (int)y0f;
    fx = (x0 < 0) ? 0.f : fx;
    fy = (y0 < 0) ? 0.f : fy;
    xq = min(max(x0, 0), W-1);
    yq = min(max(y0, 0), H-1);
}

// ---------- q10 blend (4 packed texels: 00,01,10,11) ----------
__device__ __forceinline__ V3 q10_blend(uint4 q, float fx, float fy){
    float w00 = (1.f-fx)*(1.f-fy), w01 = fx*(1.f-fy);
    float w10 = (1.f-fx)*fy,       w11 = fx*fy;
    float r = (float)(q.x & 1023u)*w00 + (float)(q.y & 1023u)*w01
            + (float)(q.z & 1023u)*w10 + (float)(q.w & 1023u)*w11;
    float g = (float)((q.x>>10) & 1023u)*w00 + (float)((q.y>>10) & 1023u)*w01
            + (float)((q.z>>10) & 1023u)*w10 + (float)((q.w>>10) & 1023u)*w11;
    float b = (float)((q.x>>20) & 1023u)*w00 + (float)((q.y>>20) & 1023u)*w01
            + (float)((q.z>>20) & 1023u)*w10 + (float)((q.w>>20) & 1023u)*w11;
    const float s = 1.0f/1023.0f;
    return { r*s, g*s, b*s };
}

__device__ __forceinline__ void q10_fg(uint4 q, float fx, float fy,
                                       float& fa, float& fb){
    float w00 = (1.f-fx)*(1.f-fy), w01 = fx*(1.f-fy);
    float w10 = (1.f-fx)*fy,       w11 = fx*fy;
    float a00 = (float)(q.x & 1023u),        b00 = (float)((q.x>>10) & 1023u);
    float a01 = (float)((q.x>>20) & 1023u),  b01 = (float)(q.y & 1023u);
    float a10 = (float)((q.y>>10) & 1023u),  b10 = (float)((q.y>>20) & 1023u);
    float a11 = (float)(q.z & 1023u),        b11 = (float)((q.z>>10) & 1023u);
    const float s = 1.0f/1023.0f;
    fa = (a00*w00 + a01*w01 + a10*w10 + a11*w11) * s;
    fb = (b00*w00 + b01*w01 + b10*w10 + b11*w11) * s;
}

// ---------- LDS compact-q10 bilinear (4-corner clamp) ----------
__device__ __forceinline__ V3 lds_bilin(const unsigned* lds, int base, int R,
                                        int face, float u, float v){
    float Rf = (float)R;
    float tu = fmaf(fmaf(u, 0.5f, 0.5f), Rf, -0.5f);
    float tv = fmaf(fmaf(v, 0.5f, 0.5f), Rf, -0.5f);
    float x0f = floorf(tu), y0f = floorf(tv);
    float fx = tu - x0f, fy = tv - y0f;
    int x0 = min(max((int)x0f,     0), R-1);
    int x1 = min(max((int)x0f + 1, 0), R-1);
    int y0 = min(max((int)y0f,     0), R-1);
    int y1 = min(max((int)y0f + 1, 0), R-1);
    const unsigned* fb = lds + base + face * R * R;
    uint4 q = make_uint4(fb[y0*R + x0], fb[y0*R + x1],
                         fb[y1*R + x0], fb[y1*R + x1]);
    // when (int)x0f<0 both x-corners clamp to 0 so fx value is irrelevant; same for y
    return q10_blend(q, fx, fy);
}

// ---------- raw f32 bilinear (reference-exact; used for s0 level and fallback) ----------
__device__ __forceinline__ V3 bilinear_cube3(const float* __restrict__ tex, int R,
                                             int face, float u, float v){
    float Rf = (float)R;
    float tu = fmaf(fmaf(u, 0.5f, 0.5f), Rf, -0.5f);
    float tv = fmaf(fmaf(v, 0.5f, 0.5f), Rf, -0.5f);
    float x0 = floorf(tu), y0 = floorf(tv);
    float fx = tu - x0,    fy = tv - y0;
    int x0i = min(max((int)x0,     0), R-1);
    int x1i = min(max((int)x0 + 1, 0), R-1);
    int y0i = min(max((int)y0,     0), R-1);
    int y1i = min(max((int)y0 + 1, 0), R-1);
    const float* base = tex + (size_t)face * R * R * 3;
    const float* r0 = base + (size_t)y0i * R * 3;
    const float* r1 = base + (size_t)y1i * R * 3;
    float a0 = r0[3*x0i], a1 = r0[3*x0i+1], a2 = r0[3*x0i+2];
    float b0 = r0[3*x1i], b1 = r0[3*x1i+1], b2 = r0[3*x1i+2];
    float d0 = r1[3*x0i], d1 = r1[3*x0i+1], d2 = r1[3*x0i+2];
    float e0 = r1[3*x1i], e1 = r1[3*x1i+1], e2 = r1[3*x1i+2];
    float w00 = (1.f-fx)*(1.f-fy), w01 = fx*(1.f-fy);
    float w10 = (1.f-fx)*fy,       w11 = fx*fy;
    V3 out;
    out.x = a0*w00 + b0*w01 + d0*w10 + e0*w11;
    out.y = a1*w00 + b1*w01 + d1*w10 + e1*w11;
    out.z = a2*w00 + b2*w01 + d2*w10 + e2*w11;
    return out;
}

__device__ __forceinline__ void sample_fg(const float* __restrict__ lut,
                                          float u, float v, float& fa, float& fb){
    const int W = 256, H = 256;
    float tu = fmaf(u, (float)W, -0.5f);
    float tv = fmaf(v, (float)H, -0.5f);
    float x0 = floorf(tu), y0 = floorf(tv);
    float fx = tu - x0,    fy = tv - y0;
    int x0i = min(max((int)x0,     0), W-1);
    int x1i = min(max((int)x0 + 1, 0), W-1);
    int y0i = min(max((int)y0,     0), H-1);
    int y1i = min(max((int)y0 + 1, 0), H-1);
    const float2* l2 = (const float2*)lut;
    float2 a = l2[(size_t)y0i*W + x0i];
    float2 b = l2[(size_t)y0i*W + x1i];
    float2 d = l2[(size_t)y1i*W + x0i];
    float2 e = l2[(size_t)y1i*W + x1i];
    float w00 = (1.f-fx)*(1.f-fy), w01 = fx*(1.f-fy);
    float w10 = (1.f-fx)*fy,       w11 = fx*fy;
    fa = a.x*w00 + b.x*w01 + d.x*w10 + e.x*w11;
    fb = a.y*w00 + b.y*w01 + d.y*w10 + e.y*w11;
}

// ---------- linear -> srgb ----------
__device__ __forceinline__ float lin2srgb(float x){
    float xs = (x > 0.0031308f) ? x : 1.0f;
    float p  = __builtin_amdgcn_exp2f(__builtin_amdgcn_logf(xs) * (1.0f/2.4f));
    return (x > 0.0031308f) ? fmaf(1.055f, p, -0.055f) : 12.92f * x;
}

__device__ __forceinline__ float clamp01(float x){ return fminf(fmaxf(x, 0.f), 1.f); }

// ---------- per-pixel precomputed state ----------
struct PixPre {
    V3 diff_alb, spec_alb;
    int sface; float su, sv;
    int dface; float du, dv;
    int offA, RA, offB, RB; float f;
    float ndotv, rough;
};

__device__ __forceinline__ PixPre pre_pixel_v(V3 pos, V3 nrm, V3 bc, float m, float r, V3 vp)
{
    V3 wo = nrm3(v3sub(vp, pos));
    float ndv_raw = dot3(wo, nrm);
    V3 refl = nrm3(v3sub(v3scale(nrm, 2.0f*ndv_raw), wo));

    PixPre p;
    float one_m = 1.0f - m;
    p.diff_alb = v3scale(bc, one_m);
    p.spec_alb = { fmaf(m, bc.x, 0.04f*one_m),
                   fmaf(m, bc.y, 0.04f*one_m),
                   fmaf(m, bc.z, 0.04f*one_m) };
    p.ndotv = fmaxf(ndv_raw, 0.0001f);
    p.rough = r;

    const float MIN_R = 0.08f, MAX_R = 0.5f;
    float lo = (fminf(fmaxf(r, MIN_R), MAX_R) - MIN_R) / (MAX_R - MIN_R) * 4.0f;
    float hi = (fminf(fmaxf(r, MAX_R), 1.0f) - MAX_R) / (1.0f - MAX_R) + 4.0f;
    float mip = (r < MAX_R) ? lo : hi;
    mip = fminf(fmaxf(mip, 0.0f), 5.0f);
    int l0 = min((int)mip, 5);
    p.f = mip - (float)l0;
    int l1 = min(l0 + 1, 5);

    // quad-region base offsets; levels 0 (raw) and 5 (LDS) never read these
    int offA = NOFF1;
    offA = (l0 == 2) ? NOFF2 : offA; offA = (l0 == 3) ? NOFF3 : offA;
    offA = (l0 == 4) ? NOFF4 : offA;
    int offB = NOFF1;
    offB = (l1 == 2) ? NOFF2 : offB; offB = (l1 == 3) ? NOFF3 : offB;
    offB = (l1 == 4) ? NOFF4 : offB;
    p.offA = offA; p.RA = 512 >> l0;
    p.offB = offB; p.RB = 512 >> l1;

    cube_face_uv(nrm, p.dface, p.du, p.dv);
    cube_face_uv(refl, p.sface, p.su, p.sv);
    return p;
}

// ---------- q10 pack helper ----------
__device__ __forceinline__ unsigned pk3(float a, float b, float c){
    unsigned ia = __float2uint_rn(fminf(fmaxf(a, 0.f), 1.f) * 1023.f);
    unsigned ib = __float2uint_rn(fminf(fmaxf(b, 0.f), 1.f) * 1023.f);
    unsigned ic = __float2uint_rn(fminf(fmaxf(c, 0.f), 1.f) * 1023.f);
    return ia | (ib << 10) | (ic << 20);
}

// ---------- vectorized pack: s1..s4 quads + fg quads + appendix; s0 NOT touched ----------
// All region boundaries and all R are multiples of 4, so a 4-quad group never crosses
// a region or row boundary. 3*local floats with local % 4 == 0 -> 48B-aligned float4s.
__global__ __launch_bounds__(256)
void pack_q10r(const float* __restrict__ s1, const float* __restrict__ s2,
               const float* __restrict__ s3, const float* __restrict__ s4,
               const float* __restrict__ s5, const float* __restrict__ diffuse,
               const float* __restrict__ fg_lut,
               uint4* __restrict__ qws)
{
    int t = blockIdx.x * blockDim.x + threadIdx.x;
    if (t >= NQ4_TOTAL) return;

    if (t >= NQ4_SPEC + NQ4_FG) {
        // appendix: 4 compact texels (diffuse then mip5); boundary APP_M5=1536 is /4
        int local4 = (t - NQ4_SPEC - NQ4_FG) * 4;
        const float* src; int idx;
        if (local4 < APP_M5) { src = diffuse; idx = local4; }
        else                 { src = s5;      idx = local4 - APP_M5; }
        const float4* sp = (const float4*)(src + 3*idx);
        float4 a = sp[0], b = sp[1], c = sp[2];
        uint4 o;
        o.x = pk3(a.x, a.y, a.z);
        o.y = pk3(a.w, b.x, b.y);
        o.z = pk3(b.z, b.w, c.x);
        o.w = pk3(c.y, c.z, c.w);
        *(uint4*)((unsigned*)(qws + NTOT_QUADS) + local4) = o;
        return;
    }

    if (t >= NQ4_SPEC) {
        // fg region: 4 quads along a row. texels x..x+4 of rows y and min(y+1,255).
        int local = (t - NQ4_SPEC) * 4;
        int x = local & 255, y = local >> 8;
        int y1 = (y == 255) ? y : y + 1;
        const float* r0p = fg_lut + 2*local;
        const float* r1p = fg_lut + 2*((y1 << 8) + x);
        bool edge = (x == 252);
        float4 r0a = ((const float4*)r0p)[0], r0b = ((const float4*)r0p)[1];
        float4 r1a = ((const float4*)r1p)[0], r1b = ((const float4*)r1p)[1];
        float4 r0c = *(const float4*)(r0p + (edge ? 4 : 8));
        float4 r1c = *(const float4*)(r1p + (edge ? 4 : 8));
        float a0[5], b0[5], a1[5], b1[5];
        a0[0]=r0a.x; b0[0]=r0a.y; a0[1]=r0a.z; b0[1]=r0a.w;
        a0[2]=r0b.x; b0[2]=r0b.y; a0[3]=r0b.z; b0[3]=r0b.w;
        a0[4]= edge ? r0b.z : r0c.x; b0[4]= edge ? r0b.w : r0c.y;
        a1[0]=r1a.x; b1[0]=r1a.y; a1[1]=r1a.z; b1[1]=r1a.w;
        a1[2]=r1b.x; b1[2]=r1b.y; a1[3]=r1b.z; b1[3]=r1b.w;
        a1[4]= edge ? r1b.z : r1c.x; b1[4]= edge ? r1b.w : r1c.y;
        #pragma unroll
        for (int k = 0; k < 4; ++k) {
            uint4 q;
            q.x = pk3(a0[k], b0[k], a0[k+1]);
            q.y = pk3(b0[k+1], a1[k], b1[k]);
            q.z = pk3(a1[k+1], b1[k+1], 0.f);
            q.w = 0u;
            qws[(size_t)NFG_OFF + local + k] = q;
        }
        return;
    }

    // spec quad region (s1..s4): 4 quads along a row
    int local4q = t * 4;
    const float* src; int local; int Rm;
    if      (local4q >= NOFF4) { src = s4; local = local4q - NOFF4; Rm = 31;  }
    else if (local4q >= NOFF3) { src = s3; local = local4q - NOFF3; Rm = 63;  }
    else if (local4q >= NOFF2) { src = s2; local = local4q - NOFF2; Rm = 127; }
    else                       { src = s1; local = local4q;         Rm = 255; }
    int x = local & Rm;
    int y = (local / (Rm + 1)) & Rm;
    int rowUp = (y == Rm) ? 0 : (Rm + 1);
    const float* r0p = src + 3*local;
    const float* r1p = src + 3*(local + rowUp);
    bool edge = (x + 4 > Rm);
    float4 A0 = ((const float4*)r0p)[0], A1 = ((const float4*)r0p)[1], A2 = ((const float4*)r0p)[2];
    float4 B0 = ((const float4*)r1p)[0], B1 = ((const float4*)r1p)[1], B2 = ((const float4*)r1p)[2];
    float4 A3 = *(const float4*)(r0p + (edge ? 8 : 12));
    float4 B3 = *(const float4*)(r1p + (edge ? 8 : 12));
    unsigned t0[5], t1[5];
    t0[0] = pk3(A0.x, A0.y, A0.z);
    t0[1] = pk3(A0.w, A1.x, A1.y);
    t0[2] = pk3(A1.z, A1.w, A2.x);
    t0[3] = pk3(A2.y, A2.z, A2.w);
    t0[4] = edge ? t0[3] : pk3(A3.x, A3.y, A3.z);
    t1[0] = pk3(B0.x, B0.y, B0.z);
    t1[1] = pk3(B0.w, B1.x, B1.y);
    t1[2] = pk3(B1.z, B1.w, B2.x);
    t1[3] = pk3(B2.y, B2.z, B2.w);
    t1[4] = edge ? t1[3] : pk3(B3.x, B3.y, B3.z);
    #pragma unroll
    for (int k = 0; k < 4; ++k) {
        uint4 q;
        q.x = t0[k];
        q.y = t0[k+1];
        q.z = t1[k];
        q.w = t1[k+1];
        qws[(size_t)local4q + k] = q;
    }
}

// ---------- spec sampler: raw f32 for s0, LDS for mip5, global quads otherwise ----------
__device__ __forceinline__ V3 sample_spec(const uint4* __restrict__ qws,
                                          const unsigned* lds,
                                          const float* __restrict__ s0raw,
                                          int off, int R, int face, float u, float v){
    if (R == 512)
        return bilinear_cube3(s0raw, 512, face, u, v);
    if (R == 16)
        return lds_bilin(lds, APP_M5, 16, face, u, v);
    int x, y; float fx, fy;
    quad_coord_cube(u, v, R, x, y, fx, fy);
    size_t q = (size_t)off + (size_t)face * R * R + (size_t)y * R + x;
    return q10_blend(qws[q], fx, fy);
}

// ---------- full per-pixel shade ----------
__device__ __forceinline__ void shade_px(V3 pos, V3 nrm, V3 bc, float m, float r, V3 vp,
                                         const uint4* __restrict__ qws,
                                         const unsigned* lds,
                                         const float* __restrict__ s0raw, float* o)
{
    PixPre p = pre_pixel_v(pos, nrm, bc, m, r, vp);

    // fg (global, L2-resident) — issue first
    int fx_, fy_; float ffx, ffy;
    quad_coord_2d(p.ndotv, p.rough, 256, 256, fx_, fy_, ffx, ffy);
    uint4 F = qws[(size_t)NFG_OFF + (size_t)fy_ * 256 + fx_];

    V3 specA = sample_spec(qws, lds, s0raw, p.offA, p.RA, p.sface, p.su, p.sv);
    V3 specB = sample_spec(qws, lds, s0raw, p.offB, p.RB, p.sface, p.su, p.sv);
    V3 ambient = lds_bilin(lds, APP_DIFF, 16, p.dface, p.du, p.dv);

    float fa, fb;
    q10_fg(F, ffx, ffy, fa, fb);

    V3 spec = { specA.x + (specB.x - specA.x) * p.f,
                specA.y + (specB.y - specA.y) * p.f,
                specA.z + (specB.z - specA.z) * p.f };
    V3 reflc = { fmaf(p.spec_alb.x, fa, fb),
                 fmaf(p.spec_alb.y, fa, fb),
                 fmaf(p.spec_alb.z, fa, fb) };
    V3 rgb = v3add(v3mul(spec, reflc), v3mul(ambient, p.diff_alb));

    o[0] = lin2srgb(clamp01(rgb.x));
    o[1] = lin2srgb(clamp01(rgb.y));
    o[2] = lin2srgb(clamp01(rgb.z));
}

// ---------- main kernel: 4 px/thread, vectorized gbuffer I/O, raw s0 ----------
__global__ __launch_bounds__(256)
void envlight_q10r(const float* __restrict__ gb_pos,
                   const float* __restrict__ gb_normal,
                   const float* __restrict__ basecolor,
                   const float* __restrict__ metallic,
                   const float* __restrict__ roughness,
                   const float* __restrict__ view_pos,
                   const float* __restrict__ s0,
                   const uint4* __restrict__ qws,
                   float* __restrict__ out,
                   int n)
{
    __shared__ unsigned lds_small[APP_UINTS];   // 12 KB: diffuse + mip5
    {
        const uint4* app4 = qws + NTOT_QUADS;
        uint4* l4 = (uint4*)lds_small;
        for (int k = threadIdx.x; k < APP_UINTS/4; k += 256)
            l4[k] = app4[k];
    }
    __syncthreads();

    int t = blockIdx.x * blockDim.x + threadIdx.x;
    int i0 = t * 4;
    if (i0 >= n) return;
    V3 vp = { view_pos[0], view_pos[1], view_pos[2] };

    if (i0 + 3 < n) {
        // i0 % 4 == 0  ->  3*i0 floats is 48B-aligned: 3 aligned float4 per array
        const float4* P = (const float4*)(gb_pos    + 3*i0);
        const float4* N = (const float4*)(gb_normal + 3*i0);
        const float4* B = (const float4*)(basecolor + 3*i0);
        float4 p0 = P[0], p1 = P[1], p2 = P[2];
        float4 n0 = N[0], n1 = N[1], n2 = N[2];
        float4 b0 = B[0], b1 = B[1], b2 = B[2];
        float4 mt = *(const float4*)(metallic  + i0);
        float4 rg = *(const float4*)(roughness + i0);

        float pf[12] = { p0.x,p0.y,p0.z,p0.w, p1.x,p1.y,p1.z,p1.w, p2.x,p2.y,p2.z,p2.w };
        float nf[12] = { n0.x,n0.y,n0.z,n0.w, n1.x,n1.y,n1.z,n1.w, n2.x,n2.y,n2.z,n2.w };
        float bf[12] = { b0.x,b0.y,b0.z,b0.w, b1.x,b1.y,b1.z,b1.w, b2.x,b2.y,b2.z,b2.w };
        float mf[4]  = { mt.x, mt.y, mt.z, mt.w };
        float rf[4]  = { rg.x, rg.y, rg.z, rg.w };
        float of[12];

        #pragma unroll
        for (int j = 0; j < 4; ++j) {
            V3 pos = { pf[3*j], pf[3*j+1], pf[3*j+2] };
            V3 nrm = { nf[3*j], nf[3*j+1], nf[3*j+2] };
            V3 bc  = { bf[3*j], bf[3*j+1], bf[3*j+2] };
            shade_px(pos, nrm, bc, mf[j], rf[j], vp, qws, lds_small, s0, of + 3*j);
        }

        float4* O = (float4*)(out + 3*i0);
        O[0] = make_float4(of[0], of[1], of[2],  of[3]);
        O[1] = make_float4(of[4], of[5], of[6],  of[7]);
        O[2] = make_float4(of[8], of[9], of[10], of[11]);
    } else {
        for (int j = 0; j < 4; ++j) {
            int i = i0 + j;
            if (i >= n) break;
            V3 pos = { gb_pos[3*i],    gb_pos[3*i+1],    gb_pos[3*i+2] };
            V3 nrm = { gb_normal[3*i], gb_normal[3*i+1], gb_normal[3*i+2] };
            V3 bc  = { basecolor[3*i], basecolor[3*i+1], basecolor[3*i+2] };
            float o[3];
            shade_px(pos, nrm, bc, metallic[i], roughness[i], vp, qws, lds_small, s0, o);
            out[3*i+0] = o[0]; out[3*i+1] = o[1]; out[3*i+2] = o[2];
        }
    }
}

// ---------- raw fallback (no workspace) ----------
__global__ __launch_bounds__(256)
void envlight_fallback(const float* __restrict__ gb_pos,
                       const float* __restrict__ gb_normal,
                       const float* __restrict__ basecolor,
                       const float* __restrict__ metallic,
                       const float* __restrict__ roughness,
                       const float* __restrict__ view_pos,
                       const float* __restrict__ diffuse,
                       const float* __restrict__ fg_lut,
                       const float* __restrict__ s0, const float* __restrict__ s1,
                       const float* __restrict__ s2, const float* __restrict__ s3,
                       const float* __restrict__ s4, const float* __restrict__ s5,
                       float* __restrict__ out, int n)
{
    int i = blockIdx.x * blockDim.x + threadIdx.x;
    if (i >= n) return;
    V3 vp = { view_pos[0], view_pos[1], view_pos[2] };
    V3 pos = { gb_pos[3*i],    gb_pos[3*i+1],    gb_pos[3*i+2] };
    V3 nrm = { gb_normal[3*i], gb_normal[3*i+1], gb_normal[3*i+2] };
    V3 bc  = { basecolor[3*i], basecolor[3*i+1], basecolor[3*i+2] };
    PixPre p = pre_pixel_v(pos, nrm, bc, metallic[i], roughness[i], vp);
    int l0 = 0;
    l0 = (p.RA == 256) ? 1 : l0; l0 = (p.RA == 128) ? 2 : l0;
    l0 = (p.RA ==  64) ? 3 : l0; l0 = (p.RA ==  32) ? 4 : l0;
    l0 = (p.RA ==  16) ? 5 : l0;
    int l1 = min(l0 + 1, 5);
    const float* tA = s0;
    tA = (l0 == 1) ? s1 : tA; tA = (l0 == 2) ? s2 : tA;
    tA = (l0 == 3) ? s3 : tA; tA = (l0 == 4) ? s4 : tA; tA = (l0 == 5) ? s5 : tA;
    const float* tB = s0;
    tB = (l1 == 1) ? s1 : tB; tB = (l1 == 2) ? s2 : tB;
    tB = (l1 == 3) ? s3 : tB; tB = (l1 == 4) ? s4 : tB; tB = (l1 == 5) ? s5 : tB;
    V3 ambient = bilinear_cube3(diffuse, 16, p.dface, p.du, p.dv);
    V3 specA   = bilinear_cube3(tA, p.RA, p.sface, p.su, p.sv);
    V3 specB   = bilinear_cube3(tB, p.RB, p.sface, p.su, p.sv);
    float fa, fb;
    sample_fg(fg_lut, p.ndotv, p.rough, fa, fb);
    V3 spec = { specA.x + (specB.x - specA.x) * p.f,
                specA.y + (specB.y - specA.y) * p.f,
                specA.z + (specB.z - specA.z) * p.f };
    V3 reflc = { fmaf(p.spec_alb.x, fa, fb),
                 fmaf(p.spec_alb.y, fa, fb),
                 fmaf(p.spec_alb.z, fa, fb) };
    V3 rgb = v3add(v3mul(spec, reflc), v3mul(ambient, p.diff_alb));
    out[3*i+0] = lin2srgb(clamp01(rgb.x));
    out[3*i+1] = lin2srgb(clamp01(rgb.y));
    out[3*i+2] = lin2srgb(clamp01(rgb.z));
}

extern "C" void kernel_launch(void* const* d_in, const int* in_sizes, int n_in,
                              void* d_out, int out_size, void* d_ws, size_t ws_size,
                              hipStream_t stream) {
    const float* gb_pos    = (const float*)d_in[0];
    const float* gb_normal = (const float*)d_in[1];
    const float* basecolor = (const float*)d_in[2];
    const float* metallic  = (const float*)d_in[3];
    const float* roughness = (const float*)d_in[4];
    const float* view_pos  = (const float*)d_in[5];
    const float* diffuse   = (const float*)d_in[6];
    const float* fg_lut    = (const float*)d_in[7];
    const float* s0        = (const float*)d_in[8];
    const float* s1        = (const float*)d_in[9];
    const float* s2        = (const float*)d_in[10];
    const float* s3        = (const float*)d_in[11];
    const float* s4        = (const float*)d_in[12];
    const float* s5        = (const float*)d_in[13];
    float* out = (float*)d_out;

    int n = in_sizes[0] / 3;
    int block = 256;

    if (ws_size >= WS_BYTES_NEW) {
        uint4* qws = (uint4*)d_ws;
        int pgrid = (NQ4_TOTAL + block - 1) / block;
        pack_q10r<<<pgrid, block, 0, stream>>>(s1, s2, s3, s4, s5,
                                               diffuse, fg_lut, qws);
        int t4 = (n + 3) / 4;
        int mgrid = (t4 + block - 1) / block;
        envlight_q10r<<<mgrid, block, 0, stream>>>(gb_pos, gb_normal, basecolor,
            metallic, roughness, view_pos, s0, qws, out, n);
    } else {
        int grid = (n + block - 1) / block;
        envlight_fallback<<<grid, block, 0, stream>>>(gb_pos, gb_normal, basecolor,
            metallic, roughness, view_pos, diffuse, fg_lut,
            s0, s1, s2, s3, s4, s5, out, n);
    }
}

// Round 3
// 151.015 us; speedup vs baseline: 1.0316x; 1.0048x over previous
//
#include <hip/hip_runtime.h>
#include <hip/hip_fp16.h>

// ---------- small vector helpers ----------
struct V3 { float x, y, z; };

__device__ __forceinline__ V3 v3add(V3 a, V3 b){ return {a.x+b.x, a.y+b.y, a.z+b.z}; }
__device__ __forceinline__ V3 v3sub(V3 a, V3 b){ return {a.x-b.x, a.y-b.y, a.z-b.z}; }
__device__ __forceinline__ V3 v3scale(V3 a, float s){ return {a.x*s, a.y*s, a.z*s}; }
__device__ __forceinline__ V3 v3mul(V3 a, V3 b){ return {a.x*b.x, a.y*b.y, a.z*b.z}; }
__device__ __forceinline__ float dot3(V3 a, V3 b){ return fmaf(a.x,b.x, fmaf(a.y,b.y, a.z*b.z)); }
__device__ __forceinline__ V3 nrm3(V3 a){
    float s = rsqrtf(fmaxf(dot3(a,a), 1e-20f));
    return v3scale(a, s);
}

// ---------- quad layout (s0 raw-sampled in main; s5/diffuse: LDS appendix only) ----------
//   s1 (R=256): [0, 393216)
//   s2 (R=128): [393216, 491520)
//   s3 (R= 64): [491520, 516096)
//   s4 (R= 32): [516096, 522240)
//   fg  (256²): [522240, 587776)
#define NOFF1 0
#define NOFF2 393216
#define NOFF3 491520
#define NOFF4 516096
#define SPEC4_COUNT 522240
#define NFG_OFF 522240
#define NTOT_QUADS 587776
// appendix: compact 1-uint-per-texel q10 for diffuse(1536) + mip5(1536)
#define APP_DIFF 0
#define APP_M5   1536
#define APP_UINTS 3072
#define WS_BYTES_NEW ((size_t)NTOT_QUADS * 16 + (size_t)APP_UINTS * 4)   // 9,416,704

// pack thread counts (4 quads / 4 texels per thread)
#define NQ4_SPEC (SPEC4_COUNT/4)    // 130,560
#define NQ4_FG   (65536/4)          // 16,384
#define NQ4_APP  (APP_UINTS/4)      // 768
#define NQ4_TOTAL (NQ4_SPEC + NQ4_FG + NQ4_APP)   // 147,712 = 577*256

// ---------- cube face / uv ----------
__device__ __forceinline__ void cube_face_uv(V3 d, int& face, float& u, float& v){
    float ax = fabsf(d.x), ay = fabsf(d.y), az = fabsf(d.z);
    bool is_x = (ax >= ay) && (ax >= az);
    bool is_y = (!is_x) && (ay >= az);
    face = is_x ? (d.x >= 0.f ? 0 : 1)
                : (is_y ? (d.y >= 0.f ? 2 : 3)
                        : (d.z >= 0.f ? 4 : 5));
    float ma = fmaxf(is_x ? ax : (is_y ? ay : az), 1e-20f);
    float un = (face == 0) ? -d.z : (face == 1) ? d.z : (face == 5) ? -d.x : d.x;
    float vn = (face == 2) ?  d.z : (face == 3) ? -d.z : -d.y;
    float inv = 1.0f / ma;
    u = un * inv;
    v = vn * inv;
}

// ---------- bilinear coords ----------
__device__ __forceinline__ void quad_coord_cube(float u, float v, int R,
                                                int& xq, int& yq, float& fx, float& fy){
    float Rf = (float)R;
    float tu = fmaf(fmaf(u, 0.5f, 0.5f), Rf, -0.5f);
    float tv = fmaf(fmaf(v, 0.5f, 0.5f), Rf, -0.5f);
    float x0f = floorf(tu), y0f = floorf(tv);
    fx = tu - x0f; fy = tv - y0f;
    int x0 = (int)x0f, y0 = (int)y0f;
    fx = (x0 < 0) ? 0.f : fx;
    fy = (y0 < 0) ? 0.f : fy;
    xq = min(max(x0, 0), R-1);
    yq = min(max(y0, 0), R-1);
}

__device__ __forceinline__ void quad_coord_2d(float u, float v, int W, int H,
                                              int& xq, int& yq, float& fx, float& fy){
    float tu = fmaf(u, (float)W, -0.5f);
    float tv = fmaf(v, (float)H, -0.5f);
    float x0f = floorf(tu), y0f = floorf(tv);
    fx = tu - x0f; fy = tv - y0f;
    int x0 = (int)x0f, y0 = (int)y0f;
    fx = (x0 < 0) ? 0.f : fx;
    fy = (y0 < 0) ? 0.f : fy;
    xq = min(max(x0, 0), W-1);
    yq = min(max(y0, 0), H-1);
}

// ---------- q10 blend (4 packed texels: 00,01,10,11) ----------
__device__ __forceinline__ V3 q10_blend(uint4 q, float fx, float fy){
    float w00 = (1.f-fx)*(1.f-fy), w01 = fx*(1.f-fy);
    float w10 = (1.f-fx)*fy,       w11 = fx*fy;
    float r = (float)(q.x & 1023u)*w00 + (float)(q.y & 1023u)*w01
            + (float)(q.z & 1023u)*w10 + (float)(q.w & 1023u)*w11;
    float g = (float)((q.x>>10) & 1023u)*w00 + (float)((q.y>>10) & 1023u)*w01
            + (float)((q.z>>10) & 1023u)*w10 + (float)((q.w>>10) & 1023u)*w11;
    float b = (float)((q.x>>20) & 1023u)*w00 + (float)((q.y>>20) & 1023u)*w01
            + (float)((q.z>>20) & 1023u)*w10 + (float)((q.w>>20) & 1023u)*w11;
    const float s = 1.0f/1023.0f;
    return { r*s, g*s, b*s };
}

__device__ __forceinline__ void q10_fg(uint4 q, float fx, float fy,
                                       float& fa, float& fb){
    float w00 = (1.f-fx)*(1.f-fy), w01 = fx*(1.f-fy);
    float w10 = (1.f-fx)*fy,       w11 = fx*fy;
    float a00 = (float)(q.x & 1023u),        b00 = (float)((q.x>>10) & 1023u);
    float a01 = (float)((q.x>>20) & 1023u),  b01 = (float)(q.y & 1023u);
    float a10 = (float)((q.y>>10) & 1023u),  b10 = (float)((q.y>>20) & 1023u);
    float a11 = (float)(q.z & 1023u),        b11 = (float)((q.z>>10) & 1023u);
    const float s = 1.0f/1023.0f;
    fa = (a00*w00 + a01*w01 + a10*w10 + a11*w11) * s;
    fb = (b00*w00 + b01*w01 + b10*w10 + b11*w11) * s;
}

// ---------- LDS compact-q10 bilinear (4-corner clamp) ----------
__device__ __forceinline__ V3 lds_bilin(const unsigned* lds, int base, int R,
                                        int face, float u, float v){
    float Rf = (float)R;
    float tu = fmaf(fmaf(u, 0.5f, 0.5f), Rf, -0.5f);
    float tv = fmaf(fmaf(v, 0.5f, 0.5f), Rf, -0.5f);
    float x0f = floorf(tu), y0f = floorf(tv);
    float fx = tu - x0f, fy = tv - y0f;
    int x0 = min(max((int)x0f,     0), R-1);
    int x1 = min(max((int)x0f + 1, 0), R-1);
    int y0 = min(max((int)y0f,     0), R-1);
    int y1 = min(max((int)y0f + 1, 0), R-1);
    const unsigned* fb = lds + base + face * R * R;
    uint4 q = make_uint4(fb[y0*R + x0], fb[y0*R + x1],
                         fb[y1*R + x0], fb[y1*R + x1]);
    // when (int)x0f<0 both x-corners clamp to 0 so fx value is irrelevant; same for y
    return q10_blend(q, fx, fy);
}

// ---------- raw f32 bilinear (reference-exact; used for s0 level and fallback) ----------
__device__ __forceinline__ V3 bilinear_cube3(const float* __restrict__ tex, int R,
                                             int face, float u, float v){
    float Rf = (float)R;
    float tu = fmaf(fmaf(u, 0.5f, 0.5f), Rf, -0.5f);
    float tv = fmaf(fmaf(v, 0.5f, 0.5f), Rf, -0.5f);
    float x0 = floorf(tu), y0 = floorf(tv);
    float fx = tu - x0,    fy = tv - y0;
    int x0i = min(max((int)x0,     0), R-1);
    int x1i = min(max((int)x0 + 1, 0), R-1);
    int y0i = min(max((int)y0,     0), R-1);
    int y1i = min(max((int)y0 + 1, 0), R-1);
    const float* base = tex + (size_t)face * R * R * 3;
    const float* r0 = base + (size_t)y0i * R * 3;
    const float* r1 = base + (size_t)y1i * R * 3;
    float a0 = r0[3*x0i], a1 = r0[3*x0i+1], a2 = r0[3*x0i+2];
    float b0 = r0[3*x1i], b1 = r0[3*x1i+1], b2 = r0[3*x1i+2];
    float d0 = r1[3*x0i], d1 = r1[3*x0i+1], d2 = r1[3*x0i+2];
    float e0 = r1[3*x1i], e1 = r1[3*x1i+1], e2 = r1[3*x1i+2];
    float w00 = (1.f-fx)*(1.f-fy), w01 = fx*(1.f-fy);
    float w10 = (1.f-fx)*fy,       w11 = fx*fy;
    V3 out;
    out.x = a0*w00 + b0*w01 + d0*w10 + e0*w11;
    out.y = a1*w00 + b1*w01 + d1*w10 + e1*w11;
    out.z = a2*w00 + b2*w01 + d2*w10 + e2*w11;
    return out;
}

__device__ __forceinline__ void sample_fg(const float* __restrict__ lut,
                                          float u, float v, float& fa, float& fb){
    const int W = 256, H = 256;
    float tu = fmaf(u, (float)W, -0.5f);
    float tv = fmaf(v, (float)H, -0.5f);
    float x0 = floorf(tu), y0 = floorf(tv);
    float fx = tu - x0,    fy = tv - y0;
    int x0i = min(max((int)x0,     0), W-1);
    int x1i = min(max((int)x0 + 1, 0), W-1);
    int y0i = min(max((int)y0,     0), H-1);
    int y1i = min(max((int)y0 + 1, 0), H-1);
    const float2* l2 = (const float2*)lut;
    float2 a = l2[(size_t)y0i*W + x0i];
    float2 b = l2[(size_t)y0i*W + x1i];
    float2 d = l2[(size_t)y1i*W + x0i];
    float2 e = l2[(size_t)y1i*W + x1i];
    float w00 = (1.f-fx)*(1.f-fy), w01 = fx*(1.f-fy);
    float w10 = (1.f-fx)*fy,       w11 = fx*fy;
    fa = a.x*w00 + b.x*w01 + d.x*w10 + e.x*w11;
    fb = a.y*w00 + b.y*w01 + d.y*w10 + e.y*w11;
}

// ---------- linear -> srgb ----------
__device__ __forceinline__ float lin2srgb(float x){
    float xs = (x > 0.0031308f) ? x : 1.0f;
    float p  = __builtin_amdgcn_exp2f(__builtin_amdgcn_logf(xs) * (1.0f/2.4f));
    return (x > 0.0031308f) ? fmaf(1.055f, p, -0.055f) : 12.92f * x;
}

__device__ __forceinline__ float clamp01(float x){ return fminf(fmaxf(x, 0.f), 1.f); }

// ---------- per-pixel precomputed state ----------
struct PixPre {
    V3 diff_alb, spec_alb;
    int sface; float su, sv;
    int dface; float du, dv;
    int offA, RA, offB, RB; float f;
    float ndotv, rough;
};

__device__ __forceinline__ PixPre pre_pixel_v(V3 pos, V3 nrm, V3 bc, float m, float r, V3 vp)
{
    V3 wo = nrm3(v3sub(vp, pos));
    float ndv_raw = dot3(wo, nrm);
    V3 refl = nrm3(v3sub(v3scale(nrm, 2.0f*ndv_raw), wo));

    PixPre p;
    float one_m = 1.0f - m;
    p.diff_alb = v3scale(bc, one_m);
    p.spec_alb = { fmaf(m, bc.x, 0.04f*one_m),
                   fmaf(m, bc.y, 0.04f*one_m),
                   fmaf(m, bc.z, 0.04f*one_m) };
    p.ndotv = fmaxf(ndv_raw, 0.0001f);
    p.rough = r;

    const float MIN_R = 0.08f, MAX_R = 0.5f;
    float lo = (fminf(fmaxf(r, MIN_R), MAX_R) - MIN_R) / (MAX_R - MIN_R) * 4.0f;
    float hi = (fminf(fmaxf(r, MAX_R), 1.0f) - MAX_R) / (1.0f - MAX_R) + 4.0f;
    float mip = (r < MAX_R) ? lo : hi;
    mip = fminf(fmaxf(mip, 0.0f), 5.0f);
    int l0 = min((int)mip, 5);
    p.f = mip - (float)l0;
    int l1 = min(l0 + 1, 5);

    // quad-region base offsets; levels 0 (raw) and 5 (LDS) never read these
    int offA = NOFF1;
    offA = (l0 == 2) ? NOFF2 : offA; offA = (l0 == 3) ? NOFF3 : offA;
    offA = (l0 == 4) ? NOFF4 : offA;
    int offB = NOFF1;
    offB = (l1 == 2) ? NOFF2 : offB; offB = (l1 == 3) ? NOFF3 : offB;
    offB = (l1 == 4) ? NOFF4 : offB;
    p.offA = offA; p.RA = 512 >> l0;
    p.offB = offB; p.RB = 512 >> l1;

    cube_face_uv(nrm, p.dface, p.du, p.dv);
    cube_face_uv(refl, p.sface, p.su, p.sv);
    return p;
}

// ---------- q10 pack helper ----------
__device__ __forceinline__ unsigned pk3(float a, float b, float c){
    unsigned ia = __float2uint_rn(fminf(fmaxf(a, 0.f), 1.f) * 1023.f);
    unsigned ib = __float2uint_rn(fminf(fmaxf(b, 0.f), 1.f) * 1023.f);
    unsigned ic = __float2uint_rn(fminf(fmaxf(c, 0.f), 1.f) * 1023.f);
    return ia | (ib << 10) | (ic << 20);
}

// ---------- vectorized pack: s1..s4 quads + fg quads + appendix; s0 NOT touched ----------
__global__ __launch_bounds__(256)
void pack_q10r(const float* __restrict__ s1, const float* __restrict__ s2,
               const float* __restrict__ s3, const float* __restrict__ s4,
               const float* __restrict__ s5, const float* __restrict__ diffuse,
               const float* __restrict__ fg_lut,
               uint4* __restrict__ qws)
{
    int t = blockIdx.x * blockDim.x + threadIdx.x;
    if (t >= NQ4_TOTAL) return;

    if (t >= NQ4_SPEC + NQ4_FG) {
        // appendix: 4 compact texels (diffuse then mip5); boundary APP_M5=1536 is /4
        int local4 = (t - NQ4_SPEC - NQ4_FG) * 4;
        const float* src; int idx;
        if (local4 < APP_M5) { src = diffuse; idx = local4; }
        else                 { src = s5;      idx = local4 - APP_M5; }
        const float4* sp = (const float4*)(src + 3*idx);
        float4 a = sp[0], b = sp[1], c = sp[2];
        uint4 o;
        o.x = pk3(a.x, a.y, a.z);
        o.y = pk3(a.w, b.x, b.y);
        o.z = pk3(b.z, b.w, c.x);
        o.w = pk3(c.y, c.z, c.w);
        *(uint4*)((unsigned*)(qws + NTOT_QUADS) + local4) = o;
        return;
    }

    if (t >= NQ4_SPEC) {
        // fg region: 4 quads along a row. texels x..x+4 of rows y and min(y+1,255).
        int local = (t - NQ4_SPEC) * 4;
        int x = local & 255, y = local >> 8;
        int y1 = (y == 255) ? y : y + 1;
        const float* r0p = fg_lut + 2*local;
        const float* r1p = fg_lut + 2*((y1 << 8) + x);
        bool edge = (x == 252);
        float4 r0a = ((const float4*)r0p)[0], r0b = ((const float4*)r0p)[1];
        float4 r1a = ((const float4*)r1p)[0], r1b = ((const float4*)r1p)[1];
        float4 r0c = *(const float4*)(r0p + (edge ? 4 : 8));
        float4 r1c = *(const float4*)(r1p + (edge ? 4 : 8));
        float a0[5], b0[5], a1[5], b1[5];
        a0[0]=r0a.x; b0[0]=r0a.y; a0[1]=r0a.z; b0[1]=r0a.w;
        a0[2]=r0b.x; b0[2]=r0b.y; a0[3]=r0b.z; b0[3]=r0b.w;
        a0[4]= edge ? r0b.z : r0c.x; b0[4]= edge ? r0b.w : r0c.y;
        a1[0]=r1a.x; b1[0]=r1a.y; a1[1]=r1a.z; b1[1]=r1a.w;
        a1[2]=r1b.x; b1[2]=r1b.y; a1[3]=r1b.z; b1[3]=r1b.w;
        a1[4]= edge ? r1b.z : r1c.x; b1[4]= edge ? r1b.w : r1c.y;
        #pragma unroll
        for (int k = 0; k < 4; ++k) {
            uint4 q;
            q.x = pk3(a0[k], b0[k], a0[k+1]);
            q.y = pk3(b0[k+1], a1[k], b1[k]);
            q.z = pk3(a1[k+1], b1[k+1], 0.f);
            q.w = 0u;
            qws[(size_t)NFG_OFF + local + k] = q;
        }
        return;
    }

    // spec quad region (s1..s4): 4 quads along a row
    int local4q = t * 4;
    const float* src; int local; int Rm;
    if      (local4q >= NOFF4) { src = s4; local = local4q - NOFF4; Rm = 31;  }
    else if (local4q >= NOFF3) { src = s3; local = local4q - NOFF3; Rm = 63;  }
    else if (local4q >= NOFF2) { src = s2; local = local4q - NOFF2; Rm = 127; }
    else                       { src = s1; local = local4q;         Rm = 255; }
    int x = local & Rm;
    int y = (local / (Rm + 1)) & Rm;
    int rowUp = (y == Rm) ? 0 : (Rm + 1);
    const float* r0p = src + 3*local;
    const float* r1p = src + 3*(local + rowUp);
    bool edge = (x + 4 > Rm);
    float4 A0 = ((const float4*)r0p)[0], A1 = ((const float4*)r0p)[1], A2 = ((const float4*)r0p)[2];
    float4 B0 = ((const float4*)r1p)[0], B1 = ((const float4*)r1p)[1], B2 = ((const float4*)r1p)[2];
    float4 A3 = *(const float4*)(r0p + (edge ? 8 : 12));
    float4 B3 = *(const float4*)(r1p + (edge ? 8 : 12));
    unsigned t0[5], t1[5];
    t0[0] = pk3(A0.x, A0.y, A0.z);
    t0[1] = pk3(A0.w, A1.x, A1.y);
    t0[2] = pk3(A1.z, A1.w, A2.x);
    t0[3] = pk3(A2.y, A2.z, A2.w);
    t0[4] = edge ? t0[3] : pk3(A3.x, A3.y, A3.z);
    t1[0] = pk3(B0.x, B0.y, B0.z);
    t1[1] = pk3(B0.w, B1.x, B1.y);
    t1[2] = pk3(B1.z, B1.w, B2.x);
    t1[3] = pk3(B2.y, B2.z, B2.w);
    t1[4] = edge ? t1[3] : pk3(B3.x, B3.y, B3.z);
    #pragma unroll
    for (int k = 0; k < 4; ++k) {
        uint4 q;
        q.x = t0[k];
        q.y = t0[k+1];
        q.z = t1[k];
        q.w = t1[k+1];
        qws[(size_t)local4q + k] = q;
    }
}

// ---------- spec sampler: raw f32 for s0, LDS for mip5, global quads otherwise ----------
__device__ __forceinline__ V3 sample_spec(const uint4* __restrict__ qws,
                                          const unsigned* lds,
                                          const float* __restrict__ s0raw,
                                          int off, int R, int face, float u, float v){
    if (R == 512)
        return bilinear_cube3(s0raw, 512, face, u, v);
    if (R == 16)
        return lds_bilin(lds, APP_M5, 16, face, u, v);
    int x, y; float fx, fy;
    quad_coord_cube(u, v, R, x, y, fx, fy);
    size_t q = (size_t)off + (size_t)face * R * R + (size_t)y * R + x;
    return q10_blend(qws[q], fx, fy);
}

// ---------- full per-pixel shade ----------
__device__ __forceinline__ void shade_px(V3 pos, V3 nrm, V3 bc, float m, float r, V3 vp,
                                         const uint4* __restrict__ qws,
                                         const unsigned* lds,
                                         const float* __restrict__ s0raw, float* o)
{
    PixPre p = pre_pixel_v(pos, nrm, bc, m, r, vp);

    // fg (global, L2-resident) — issue first
    int fx_, fy_; float ffx, ffy;
    quad_coord_2d(p.ndotv, p.rough, 256, 256, fx_, fy_, ffx, ffy);
    uint4 F = qws[(size_t)NFG_OFF + (size_t)fy_ * 256 + fx_];

    V3 specA = sample_spec(qws, lds, s0raw, p.offA, p.RA, p.sface, p.su, p.sv);
    V3 specB = sample_spec(qws, lds, s0raw, p.offB, p.RB, p.sface, p.su, p.sv);
    V3 ambient = lds_bilin(lds, APP_DIFF, 16, p.dface, p.du, p.dv);

    float fa, fb;
    q10_fg(F, ffx, ffy, fa, fb);

    V3 spec = { specA.x + (specB.x - specA.x) * p.f,
                specA.y + (specB.y - specA.y) * p.f,
                specA.z + (specB.z - specA.z) * p.f };
    V3 reflc = { fmaf(p.spec_alb.x, fa, fb),
                 fmaf(p.spec_alb.y, fa, fb),
                 fmaf(p.spec_alb.z, fa, fb) };
    V3 rgb = v3add(v3mul(spec, reflc), v3mul(ambient, p.diff_alb));

    o[0] = lin2srgb(clamp01(rgb.x));
    o[1] = lin2srgb(clamp01(rgb.y));
    o[2] = lin2srgb(clamp01(rgb.z));
}

// ---------- main kernel: 2 px/thread (2048 blocks -> 32 waves/CU), float2 gbuffer I/O ----------
__global__ __launch_bounds__(256)
void envlight_q10r2(const float* __restrict__ gb_pos,
                    const float* __restrict__ gb_normal,
                    const float* __restrict__ basecolor,
                    const float* __restrict__ metallic,
                    const float* __restrict__ roughness,
                    const float* __restrict__ view_pos,
                    const float* __restrict__ s0,
                    const uint4* __restrict__ qws,
                    float* __restrict__ out,
                    int n)
{
    __shared__ unsigned lds_small[APP_UINTS];   // 12 KB: diffuse + mip5
    {
        const uint4* app4 = qws + NTOT_QUADS;
        uint4* l4 = (uint4*)lds_small;
        for (int k = threadIdx.x; k < APP_UINTS/4; k += 256)
            l4[k] = app4[k];
    }
    __syncthreads();

    int t = blockIdx.x * blockDim.x + threadIdx.x;
    int i0 = t * 2;
    if (i0 >= n) return;
    V3 vp = { view_pos[0], view_pos[1], view_pos[2] };

    if (i0 + 1 < n) {
        // i0 % 2 == 0  ->  3*i0 floats is 24B-aligned: 3 aligned float2 per array
        const float2* P = (const float2*)(gb_pos    + 3*i0);
        const float2* N = (const float2*)(gb_normal + 3*i0);
        const float2* B = (const float2*)(basecolor + 3*i0);
        float2 p0 = P[0], p1 = P[1], p2 = P[2];
        float2 n0 = N[0], n1 = N[1], n2 = N[2];
        float2 b0 = B[0], b1 = B[1], b2 = B[2];
        float2 mt = *(const float2*)(metallic  + i0);
        float2 rg = *(const float2*)(roughness + i0);

        float pf[6] = { p0.x,p0.y, p1.x,p1.y, p2.x,p2.y };
        float nf[6] = { n0.x,n0.y, n1.x,n1.y, n2.x,n2.y };
        float bf[6] = { b0.x,b0.y, b1.x,b1.y, b2.x,b2.y };
        float mf[2] = { mt.x, mt.y };
        float rf[2] = { rg.x, rg.y };
        float of[6];

        #pragma unroll
        for (int j = 0; j < 2; ++j) {
            V3 pos = { pf[3*j], pf[3*j+1], pf[3*j+2] };
            V3 nrm = { nf[3*j], nf[3*j+1], nf[3*j+2] };
            V3 bc  = { bf[3*j], bf[3*j+1], bf[3*j+2] };
            shade_px(pos, nrm, bc, mf[j], rf[j], vp, qws, lds_small, s0, of + 3*j);
        }

        float2* O = (float2*)(out + 3*i0);
        O[0] = make_float2(of[0], of[1]);
        O[1] = make_float2(of[2], of[3]);
        O[2] = make_float2(of[4], of[5]);
    } else {
        int i = i0;
        V3 pos = { gb_pos[3*i],    gb_pos[3*i+1],    gb_pos[3*i+2] };
        V3 nrm = { gb_normal[3*i], gb_normal[3*i+1], gb_normal[3*i+2] };
        V3 bc  = { basecolor[3*i], basecolor[3*i+1], basecolor[3*i+2] };
        float o[3];
        shade_px(pos, nrm, bc, metallic[i], roughness[i], vp, qws, lds_small, s0, o);
        out[3*i+0] = o[0]; out[3*i+1] = o[1]; out[3*i+2] = o[2];
    }
}

// ---------- raw fallback (no workspace) ----------
__global__ __launch_bounds__(256)
void envlight_fallback(const float* __restrict__ gb_pos,
                       const float* __restrict__ gb_normal,
                       const float* __restrict__ basecolor,
                       const float* __restrict__ metallic,
                       const float* __restrict__ roughness,
                       const float* __restrict__ view_pos,
                       const float* __restrict__ diffuse,
                       const float* __restrict__ fg_lut,
                       const float* __restrict__ s0, const float* __restrict__ s1,
                       const float* __restrict__ s2, const float* __restrict__ s3,
                       const float* __restrict__ s4, const float* __restrict__ s5,
                       float* __restrict__ out, int n)
{
    int i = blockIdx.x * blockDim.x + threadIdx.x;
    if (i >= n) return;
    V3 vp = { view_pos[0], view_pos[1], view_pos[2] };
    V3 pos = { gb_pos[3*i],    gb_pos[3*i+1],    gb_pos[3*i+2] };
    V3 nrm = { gb_normal[3*i], gb_normal[3*i+1], gb_normal[3*i+2] };
    V3 bc  = { basecolor[3*i], basecolor[3*i+1], basecolor[3*i+2] };
    PixPre p = pre_pixel_v(pos, nrm, bc, metallic[i], roughness[i], vp);
    int l0 = 0;
    l0 = (p.RA == 256) ? 1 : l0; l0 = (p.RA == 128) ? 2 : l0;
    l0 = (p.RA ==  64) ? 3 : l0; l0 = (p.RA ==  32) ? 4 : l0;
    l0 = (p.RA ==  16) ? 5 : l0;
    int l1 = min(l0 + 1, 5);
    const float* tA = s0;
    tA = (l0 == 1) ? s1 : tA; tA = (l0 == 2) ? s2 : tA;
    tA = (l0 == 3) ? s3 : tA; tA = (l0 == 4) ? s4 : tA; tA = (l0 == 5) ? s5 : tA;
    const float* tB = s0;
    tB = (l1 == 1) ? s1 : tB; tB = (l1 == 2) ? s2 : tB;
    tB = (l1 == 3) ? s3 : tB; tB = (l1 == 4) ? s4 : tB; tB = (l1 == 5) ? s5 : tB;
    V3 ambient = bilinear_cube3(diffuse, 16, p.dface, p.du, p.dv);
    V3 specA   = bilinear_cube3(tA, p.RA, p.sface, p.su, p.sv);
    V3 specB   = bilinear_cube3(tB, p.RB, p.sface, p.su, p.sv);
    float fa, fb;
    sample_fg(fg_lut, p.ndotv, p.rough, fa, fb);
    V3 spec = { specA.x + (specB.x - specA.x) * p.f,
                specA.y + (specB.y - specA.y) * p.f,
                specA.z + (specB.z - specA.z) * p.f };
    V3 reflc = { fmaf(p.spec_alb.x, fa, fb),
                 fmaf(p.spec_alb.y, fa, fb),
                 fmaf(p.spec_alb.z, fa, fb) };
    V3 rgb = v3add(v3mul(spec, reflc), v3mul(ambient, p.diff_alb));
    out[3*i+0] = lin2srgb(clamp01(rgb.x));
    out[3*i+1] = lin2srgb(clamp01(rgb.y));
    out[3*i+2] = lin2srgb(clamp01(rgb.z));
}

extern "C" void kernel_launch(void* const* d_in, const int* in_sizes, int n_in,
                              void* d_out, int out_size, void* d_ws, size_t ws_size,
                              hipStream_t stream) {
    const float* gb_pos    = (const float*)d_in[0];
    const float* gb_normal = (const float*)d_in[1];
    const float* basecolor = (const float*)d_in[2];
    const float* metallic  = (const float*)d_in[3];
    const float* roughness = (const float*)d_in[4];
    const float* view_pos  = (const float*)d_in[5];
    const float* diffuse   = (const float*)d_in[6];
    const float* fg_lut    = (const float*)d_in[7];
    const float* s0        = (const float*)d_in[8];
    const float* s1        = (const float*)d_in[9];
    const float* s2        = (const float*)d_in[10];
    const float* s3        = (const float*)d_in[11];
    const float* s4        = (const float*)d_in[12];
    const float* s5        = (const float*)d_in[13];
    float* out = (float*)d_out;

    int n = in_sizes[0] / 3;
    int block = 256;

    if (ws_size >= WS_BYTES_NEW) {
        uint4* qws = (uint4*)d_ws;
        int pgrid = (NQ4_TOTAL + block - 1) / block;
        pack_q10r<<<pgrid, block, 0, stream>>>(s1, s2, s3, s4, s5,
                                               diffuse, fg_lut, qws);
        int t2 = (n + 1) / 2;
        int mgrid = (t2 + block - 1) / block;
        envlight_q10r2<<<mgrid, block, 0, stream>>>(gb_pos, gb_normal, basecolor,
            metallic, roughness, view_pos, s0, qws, out, n);
    } else {
        int grid = (n + block - 1) / block;
        envlight_fallback<<<grid, block, 0, stream>>>(gb_pos, gb_normal, basecolor,
            metallic, roughness, view_pos, diffuse, fg_lut,
            s0, s1, s2, s3, s4, s5, out, n);
    }
}